// Round 5
// baseline (624.855 us; speedup 1.0000x reference)
//
#include <hip/hip_runtime.h>
#include <stdint.h>

// Problem constants
#define N_POINTS   34100
#define BATCH      8
#define N_GT       200
#define NLEV       5
#define NCAND      3500
#define MAX_DET    300
#define SCORE_TH   0.05f
#define NMS_TH     0.5f
#define IMG        1280.0f
#define TIE_CAP    2048
#define NBIN       4096

// Output layout (float32 flat, reference return order)
#define OUT_MATCH  0        // 8*34100
#define OUT_BOXES  272800   // 8*300*4
#define OUT_SCORES 282400   // 8*300
#define OUT_LABELS 284800   // 8*300
#define OUT_VALID  287200   // 8*300

// Workspace layout (bytes)
#define WS_KEYS    0              // u32[8*34100]   = 1,091,200
#define WS_GHIST   1091200        // u32[40*4096]   =   655,360
#define WS_PARAMS  1746560        // u32[40*2] (T,kk), pad 640
#define WS_CNT     1747200        // u32[64]: [0..7]=defCount, [8..47]=tieCount
#define WS_DEFK    1747456        // u64[8*3584]    =   229,376
#define WS_TIEK    1976832        // u64[40*2048]   =   655,360
#define WS_SBOX    2632192        // float4[8*3500] =   448,000
#define WS_SSC     3080192        // float[8*3500]  =   112,000
// total ~3.2 MB

typedef unsigned long long u64;
typedef uint32_t u32;

__device__ __forceinline__ int level_of(int p) {
    return (p < 25600) ? 0 : (p < 32000) ? 1 : (p < 33600) ? 2 : (p < 34000) ? 3 : 4;
}
__device__ __forceinline__ int loff_of(int l) {
    return (l == 0) ? 0 : (l == 1) ? 25600 : (l == 2) ? 32000 : (l == 3) ? 33600 : 34000;
}
__device__ __forceinline__ int k_of(int l) {
    return (l == 0) ? 1000 : (l == 1) ? 1000 : (l == 2) ? 1000 : (l == 3) ? 400 : 100;
}

// ---------------------------------------------------------------------------
// Kernel 0: zero histograms + counters (d_ws is poisoned before every launch)
// ---------------------------------------------------------------------------
__global__ __launch_bounds__(256)
void zero_kernel(u32* __restrict__ g) {
    const int n = (WS_CNT + 256 - WS_GHIST) / 4;   // ghist + params + cnt words
    for (int i = blockIdx.x * 256 + threadIdx.x; i < n; i += gridDim.x * 256)
        g[i] = 0u;
}

// ---------------------------------------------------------------------------
// Kernel 1: point->gt matching + sigmoid sortable key + 12-bit histogram.
// ---------------------------------------------------------------------------
__global__ __launch_bounds__(256)
void match_key_kernel(const float* __restrict__ points,
                      const float* __restrict__ gt,
                      const float* __restrict__ logits,
                      float* __restrict__ out_match,
                      u32* __restrict__ keys,
                      u32* __restrict__ ghist) {
#pragma clang fp contract(off)
    __shared__ float bx1[N_GT], by1[N_GT], bx2[N_GT], by2[N_GT], ar[N_GT];
    const int b = blockIdx.y;
    const int p = blockIdx.x * blockDim.x + threadIdx.x;

    for (int j = threadIdx.x; j < N_GT; j += blockDim.x) {
        float x1 = gt[(b * N_GT + j) * 4 + 0];
        float y1 = gt[(b * N_GT + j) * 4 + 1];
        float x2 = gt[(b * N_GT + j) * 4 + 2];
        float y2 = gt[(b * N_GT + j) * 4 + 3];
        bx1[j] = x1; by1[j] = y1; bx2[j] = x2; by2[j] = y2;
        ar[j] = (x2 - x1) * (y2 - y1);
    }
    __syncthreads();
    if (p >= N_POINTS) return;

    const float px = points[p * 2 + 0];
    const float py = points[p * 2 + 1];
    const float BIGF = 2147483648.0f;   // float32(2^31-1) rounds to 2^31
    float best = BIGF;
    int bi = -1;
#pragma unroll 4
    for (int j = 0; j < N_GT; ++j) {
        bool inside = (px >= bx1[j]) && (px <= bx2[j]) &&
                      (py >= by1[j]) && (py <= by2[j]);
        float cost = inside ? ar[j] : BIGF;
        if (cost < best) { best = cost; bi = j; }   // strict < = first-occurrence
    }
    out_match[b * N_POINTS + p] = (float)bi;

    float lg = logits[b * N_POINTS + p];
    float s = 1.0f / (1.0f + expf(-lg));
    u32 u = __float_as_uint(s);
    u32 key = (u & 0x80000000u) ? ~u : (u | 0x80000000u);
    keys[b * N_POINTS + p] = key;

    int seg = b * NLEV + level_of(p);
    atomicAdd(&ghist[seg * NBIN + (key >> 20)], 1u);
}

// ---------------------------------------------------------------------------
// Kernel 2: per-segment threshold select from histogram (one wave per segment).
// ---------------------------------------------------------------------------
__global__ __launch_bounds__(64)
void select_kernel(const u32* __restrict__ ghist, u32* __restrict__ params) {
    const int seg = blockIdx.x;            // b*5 + l
    const int l = seg % NLEV;
    const u32 K = (u32)k_of(l);
    const u32* h = ghist + seg * NBIN;
    const int lane = threadIdx.x;

    u32 S = 0;
#pragma unroll 8
    for (int i = 0; i < 64; ++i) S += h[lane * 64 + i];
    u32 acc = S;                            // suffix-sum over lanes >= lane
#pragma unroll
    for (int off = 1; off < 64; off <<= 1) {
        u32 v = (u32)__shfl_down((int)acc, off);
        if (lane + off < 64) acc += v;
    }
    u32 sfxAfter = acc - S;                 // count in lane-groups > lane
    bool hit = (sfxAfter < K) && (sfxAfter + S >= K);
    u64 bal = __ballot(hit);
    int Lg = (int)__builtin_ctzll(bal);     // unique crossing group
    u32 sfxG = (u32)__shfl((int)sfxAfter, Lg);

    u32 v = h[Lg * 64 + lane];
    u32 acc2 = v;
#pragma unroll
    for (int off = 1; off < 64; off <<= 1) {
        u32 t = (u32)__shfl_down((int)acc2, off);
        if (lane + off < 64) acc2 += t;
    }
    u32 sfx2 = sfxG + acc2 - v;             // count of all bins > this bin
    bool hit2 = (sfx2 < K) && (sfx2 + v >= K);
    if (hit2) {
        params[seg * 2 + 0] = (u32)(Lg * 64 + lane);  // T
        params[seg * 2 + 1] = K - sfx2;               // kk within bin T
    }
}

// ---------------------------------------------------------------------------
// Kernel 3: one-pass compact with wave-aggregated atomics (R4 win).
// ---------------------------------------------------------------------------
__global__ __launch_bounds__(256)
void compact_kernel(const u32* __restrict__ keys,
                    const u32* __restrict__ params,
                    u32* __restrict__ cnt,
                    u64* __restrict__ defK,
                    u64* __restrict__ tieK) {
    const int idx = blockIdx.x * 256 + threadIdx.x;
    const bool active = idx < BATCH * N_POINTS;
    int b = 0, seg = 0;
    bool isDef = false, isTie = false;
    u64 k50 = 0;
    if (active) {
        b = idx / N_POINTS;
        int p = idx - b * N_POINTS;
        u32 key = keys[idx];
        int l = level_of(p);
        seg = b * NLEV + l;
        u32 T = params[seg * 2 + 0];
        u32 digit = key >> 20;
        int idxl = p - loff_of(l);
        k50 = ((u64)key << 18) | ((u64)(7 - l) << 15) | (u64)(32767 - idxl);
        isDef = digit > T;
        isTie = digit == T;
    }
    const int lane = threadIdx.x & 63;
    const u64 below = (lane == 0) ? 0ull : (~0ull >> (64 - lane));

    u64 defMask = __ballot(isDef);
    while (defMask) {
        int leader = (int)__builtin_ctzll(defMask);
        int bb = __shfl(b, leader);
        u64 grp = __ballot(isDef && (b == bb));
        u32 base = 0;
        if (lane == leader)
            base = atomicAdd(&cnt[bb], (u32)__builtin_popcountll(grp));
        base = (u32)__shfl((int)base, leader);
        if (isDef && (b == bb)) {
            u32 pos = base + (u32)__builtin_popcountll(grp & below);
            defK[bb * 3584 + pos] = k50;
        }
        defMask &= ~grp;
    }
    u64 tieMask = __ballot(isTie);
    while (tieMask) {
        int leader = (int)__builtin_ctzll(tieMask);
        int sg = __shfl(seg, leader);
        u64 grp = __ballot(isTie && (seg == sg));
        u32 base = 0;
        if (lane == leader)
            base = atomicAdd(&cnt[8 + sg], (u32)__builtin_popcountll(grp));
        base = (u32)__shfl((int)base, leader);
        if (isTie && (seg == sg)) {
            u32 pos = base + (u32)__builtin_popcountll(grp & below);
            if (pos < TIE_CAP) tieK[sg * TIE_CAP + pos] = k50;
        }
        tieMask &= ~grp;
    }
}

// ---------------------------------------------------------------------------
// Kernel 4: per-image: resolve ties, bitonic-sort 3500 keys (pad 4096) in LDS,
// decode boxes (fp-contract off) into sorted candidate arrays.
// ---------------------------------------------------------------------------
__global__ __launch_bounds__(512)
void sortimg_kernel(const u32* __restrict__ params,
                    const u32* __restrict__ cnt,
                    const u64* __restrict__ defK,
                    const u64* __restrict__ tieK,
                    const float* __restrict__ reg,
                    const float* __restrict__ points,
                    float* __restrict__ sboxes,
                    float* __restrict__ sscores) {
#pragma clang fp contract(off)
    __shared__ u64 sk[4096];
    __shared__ u64 tb[TIE_CAP];
    __shared__ int s_base;
    const int b = blockIdx.x;
    const int tid = threadIdx.x;

    int nd = (int)cnt[b];
    for (int i = tid; i < nd; i += 512) sk[i] = defK[b * 3584 + i];
    if (tid == 0) s_base = nd;
    __syncthreads();

    for (int s = 0; s < NLEV; ++s) {
        int seg = b * NLEV + s;
        int t = (int)cnt[8 + seg];
        if (t > TIE_CAP) t = TIE_CAP;
        int kk = (int)params[seg * 2 + 1];
        for (int i = tid; i < t; i += 512) tb[i] = tieK[seg * TIE_CAP + i];
        __syncthreads();
        int base = s_base;
        for (int j = tid; j < t; j += 512) {
            u64 kj = tb[j];
            int r = 0;
            for (int i = 0; i < t; ++i) r += (tb[i] > kj) ? 1 : 0;
            if (r < kk) sk[base + r] = kj;       // unique ranks -> exact fill
        }
        __syncthreads();
        if (tid == 0) s_base = base + kk;
        __syncthreads();
    }
    const int total = s_base;                    // == 3500 by construction
    for (int i = tid; i < 4096; i += 512)
        if (i >= total) sk[i] = 0ull;
    __syncthreads();

    // bitonic sort, descending (keys unique; zeros sink)
    for (int k = 2; k <= 4096; k <<= 1) {
        for (int j = k >> 1; j > 0; j >>= 1) {
            for (int i = tid; i < 4096; i += 512) {
                int ixj = i ^ j;
                if (ixj > i) {
                    u64 a = sk[i], c = sk[ixj];
                    bool desc = ((i & k) == 0);
                    if (desc ? (a < c) : (a > c)) { sk[i] = c; sk[ixj] = a; }
                }
            }
            __syncthreads();
        }
    }

    // decode + write sorted candidates
    for (int r = tid; r < NCAND; r += 512) {
        float x1 = 0.f, y1 = 0.f, x2 = 0.f, y2 = 0.f, sc = 0.f;
        if (r < total) {
            u64 k50 = sk[r];
            int lowb = (int)(k50 & 0x3FFFFull);
            int l = 7 - (lowb >> 15);
            int idxl = 32767 - (lowb & 32767);
            int p = loff_of(l) + idxl;
            u32 key32 = (u32)(k50 >> 18);
            sc = __uint_as_float(key32 ^ 0x80000000u);
            int gp = b * N_POINTS + p;
            float l_ = reg[gp * 4 + 0] * IMG;
            float t_ = reg[gp * 4 + 1] * IMG;
            float r_ = reg[gp * 4 + 2] * IMG;
            float bb = reg[gp * 4 + 3] * IMG;
            float px = points[p * 2 + 0];
            float py = points[p * 2 + 1];
            x1 = fminf(fmaxf(px - l_, 0.0f), IMG);
            y1 = fminf(fmaxf(py - t_, 0.0f), IMG);
            x2 = fminf(fmaxf(px + r_, 0.0f), IMG);
            y2 = fminf(fmaxf(py + bb, 0.0f), IMG);
        }
        int slot = b * NCAND + r;
        sboxes[slot * 4 + 0] = x1;
        sboxes[slot * 4 + 1] = y1;
        sboxes[slot * 4 + 2] = x2;
        sboxes[slot * 4 + 3] = y2;
        sscores[slot] = sc;
    }
}

// ---------------------------------------------------------------------------
// Kernel 5: FUSED NMS (replaces mask_kernel + scan_kernel).
// One block (16 waves) per image. Suppression words sm[55] live in LDS.
// Per word: phase 1 = wave 0 decides keeps via in-wave ballots (box broadcast
// by shuffles, no dependent LDS read on the chain); phase 2 = 16 waves
// propagate each keep's suppression to its OWN future words (fw % 16 == wid,
// no write races). Only kept rows are ever computed (~300 vs mask's ~3500).
// ---------------------------------------------------------------------------
#define FUSE_T 1024
__global__ __launch_bounds__(FUSE_T)
void nms_fused_kernel(const float* __restrict__ sboxes,
                      const float* __restrict__ sscores,
                      float* __restrict__ out) {
#pragma clang fp contract(off)
    __shared__ float4 sb[3520];
    __shared__ float  sl[3520];
    __shared__ u64    sm[55];
    __shared__ int    skeep[64];
    __shared__ int    snk;
    __shared__ int    skept;

    const int b = blockIdx.x;
    const int tid = threadIdx.x;
    const int lane = tid & 63;
    const int wid = tid >> 6;

    const float4* gb = (const float4*)sboxes + b * NCAND;
    const float* gs = sscores + b * NCAND;
    for (int i = tid; i < 3520; i += FUSE_T) {
        sb[i] = (i < NCAND) ? gb[i] : make_float4(0.f, 0.f, 0.f, 0.f);
        sl[i] = (i < NCAND) ? gs[i] : 0.f;
    }
    if (tid == 0) { snk = 0; skept = 0; }
    __syncthreads();

    // init suppression words: pre-suppress below-threshold / out-of-range
    for (int w = wid; w < 55; w += 16) {
        int c = (w << 6) + lane;
        bool bad = !((c < NCAND) && (sl[c] > SCORE_TH));
        u64 bal = __ballot(bad);
        if (lane == 0) sm[w] = bal;
    }
    __syncthreads();

    float* ob = out + OUT_BOXES  + b * MAX_DET * 4;
    float* os = out + OUT_SCORES + b * MAX_DET;
    float* ol = out + OUT_LABELS + b * MAX_DET;
    float* ov = out + OUT_VALID  + b * MAX_DET;

    int keptReg = 0;                       // authoritative only in wave 0
    for (int w = 0; w < 55; ++w) {
        // ---- phase 1: wave 0 decides keeps inside word w ----
        if (wid == 0) {
            u64 cur = sm[w];
            const int wbase = w << 6;
            const float4 bj = sb[wbase + lane];
            const float a2j = (bj.z - bj.x) * (bj.w - bj.y);
            int nk = 0;
            while (keptReg < MAX_DET) {
                u64 avail = ~cur;
                if (avail == 0ull) break;
                int t = (int)__builtin_ctzll(avail);
                // broadcast keep's box from lane t registers (no LDS on chain)
                float bcx = __shfl(bj.x, t);
                float bcy = __shfl(bj.y, t);
                float bcz = __shfl(bj.z, t);
                float bcw = __shfl(bj.w, t);
                float a1 = (bcz - bcx) * (bcw - bcy);
                float x1 = fmaxf(bcx, bj.x);
                float y1 = fmaxf(bcy, bj.y);
                float x2 = fminf(bcz, bj.z);
                float y2 = fminf(bcw, bj.w);
                float inter = fmaxf(x2 - x1, 0.f) * fmaxf(y2 - y1, 0.f);
                float iou = inter / (a1 + a2j - inter + 1e-9f);
                cur |= __ballot(iou > NMS_TH) | (1ull << t);
                if (lane == 0) {
                    skeep[nk] = t;
                    ob[keptReg * 4 + 0] = bcx;
                    ob[keptReg * 4 + 1] = bcy;
                    ob[keptReg * 4 + 2] = bcz;
                    ob[keptReg * 4 + 3] = bcw;
                    os[keptReg] = sl[wbase + t];
                    ol[keptReg] = 0.0f;
                    ov[keptReg] = 1.0f;
                }
                nk++;
                keptReg++;
            }
            if (lane == 0) { snk = nk; skept = keptReg; }
        }
        __syncthreads();
        // ---- phase 2: all waves propagate keeps to their future words ----
        const int nk = snk;
        if (nk > 0) {
            const int wbase = w << 6;
            for (int fw = wid; fw < 55; fw += 16) {
                if (fw <= w) continue;
                const float4 bj = sb[(fw << 6) + lane];
                const float a2j = (bj.z - bj.x) * (bj.w - bj.y);
                u64 acc = 0ull;
                for (int k = 0; k < nk; ++k) {
                    float4 bc = sb[wbase + skeep[k]];   // broadcast read
                    float a1 = (bc.z - bc.x) * (bc.w - bc.y);
                    float x1 = fmaxf(bc.x, bj.x);
                    float y1 = fmaxf(bc.y, bj.y);
                    float x2 = fminf(bc.z, bj.z);
                    float y2 = fminf(bc.w, bj.w);
                    float inter = fmaxf(x2 - x1, 0.f) * fmaxf(y2 - y1, 0.f);
                    float iou = inter / (a1 + a2j - inter + 1e-9f);
                    acc |= __ballot(iou > NMS_TH);
                }
                if (lane == 0) sm[fw] |= acc;   // fw owned by this wave only
            }
        }
        __syncthreads();
        if (skept >= MAX_DET) break;           // uniform: published at barrier
    }

    const int kf = skept;
    for (int k = kf + tid; k < MAX_DET; k += FUSE_T) {
        ob[k * 4 + 0] = 0.f; ob[k * 4 + 1] = 0.f;
        ob[k * 4 + 2] = 0.f; ob[k * 4 + 3] = 0.f;
        os[k] = 0.f; ol[k] = -1.f; ov[k] = 0.f;
    }
}

// ---------------------------------------------------------------------------
extern "C" void kernel_launch(void* const* d_in, const int* in_sizes, int n_in,
                              void* d_out, int out_size, void* d_ws, size_t ws_size,
                              hipStream_t stream) {
    const float* points = (const float*)d_in[0];
    const float* gt     = (const float*)d_in[1];
    const float* logits = (const float*)d_in[2];
    const float* reg    = (const float*)d_in[3];
    float* out = (float*)d_out;

    u32* keys   = (u32*)((char*)d_ws + WS_KEYS);
    u32* ghist  = (u32*)((char*)d_ws + WS_GHIST);
    u32* params = (u32*)((char*)d_ws + WS_PARAMS);
    u32* cnt    = (u32*)((char*)d_ws + WS_CNT);
    u64* defK   = (u64*)((char*)d_ws + WS_DEFK);
    u64* tieK   = (u64*)((char*)d_ws + WS_TIEK);
    float* sboxes  = (float*)((char*)d_ws + WS_SBOX);
    float* sscores = (float*)((char*)d_ws + WS_SSC);

    zero_kernel<<<256, 256, 0, stream>>>(ghist);

    dim3 g1((N_POINTS + 255) / 256, BATCH);
    match_key_kernel<<<g1, 256, 0, stream>>>(points, gt, logits,
                                             out + OUT_MATCH, keys, ghist);

    select_kernel<<<BATCH * NLEV, 64, 0, stream>>>(ghist, params);

    compact_kernel<<<(BATCH * N_POINTS + 255) / 256, 256, 0, stream>>>(
        keys, params, cnt, defK, tieK);

    sortimg_kernel<<<BATCH, 512, 0, stream>>>(params, cnt, defK, tieK,
                                              reg, points, sboxes, sscores);

    nms_fused_kernel<<<BATCH, FUSE_T, 0, stream>>>(sboxes, sscores, out);
}

// Round 6
// 472.361 us; speedup vs baseline: 1.3228x; 1.3228x over previous
//
#include <hip/hip_runtime.h>
#include <stdint.h>

// Problem constants
#define N_POINTS   34100
#define BATCH      8
#define N_GT       200
#define NLEV       5
#define NCAND      3500
#define MAX_DET    300
#define SCORE_TH   0.05f
#define NMS_TH     0.5f
#define IMG        1280.0f
#define TIE_CAP    2048
#define NBIN       4096

// Output layout (float32 flat, reference return order)
#define OUT_MATCH  0        // 8*34100
#define OUT_BOXES  272800   // 8*300*4
#define OUT_SCORES 282400   // 8*300
#define OUT_LABELS 284800   // 8*300
#define OUT_VALID  287200   // 8*300

// Workspace layout (bytes)
#define WS_KEYS    0              // u32[8*34100]   = 1,091,200
#define WS_GHIST   1091200        // u32[40*4096]   =   655,360
#define WS_PARAMS  1746560        // u32[40*2] (T,kk), pad 640
#define WS_CNT     1747200        // u32[64]
#define WS_DEFK    1747456        // u64[8*3584]    =   229,376
#define WS_TIEK    1976832        // u64[40*2048]   =   655,360
#define WS_SBOX    2632192        // float4[8*3500] =   448,000
#define WS_SSC     3080192        // float[8*3500]  =   112,000
#define WS_MASK    3192192        // u64[8*98560]   = 6,307,840
#define MASK_STRIDE 98560         // words per image (packed triangle, padded)
// total ~9.5 MB

typedef unsigned long long u64;
typedef uint32_t u32;

// Packed upper-triangle row offset: row c stores words (c>>6)..54
__device__ __forceinline__ int mask_off(int c) {
    int g = c >> 6;
    return 64 * (55 * g - (g * (g - 1)) / 2) + (c - (g << 6)) * (55 - g);
}

__device__ __forceinline__ int level_of(int p) {
    return (p < 25600) ? 0 : (p < 32000) ? 1 : (p < 33600) ? 2 : (p < 34000) ? 3 : 4;
}
__device__ __forceinline__ int loff_of(int l) {
    return (l == 0) ? 0 : (l == 1) ? 25600 : (l == 2) ? 32000 : (l == 3) ? 33600 : 34000;
}
__device__ __forceinline__ int k_of(int l) {
    return (l == 0) ? 1000 : (l == 1) ? 1000 : (l == 2) ? 1000 : (l == 3) ? 400 : 100;
}

// ---------------------------------------------------------------------------
// Kernel 0: zero histograms + counters
// ---------------------------------------------------------------------------
__global__ __launch_bounds__(256)
void zero_kernel(u32* __restrict__ g) {
    const int n = (WS_CNT + 256 - WS_GHIST) / 4;
    for (int i = blockIdx.x * 256 + threadIdx.x; i < n; i += gridDim.x * 256)
        g[i] = 0u;
}

// ---------------------------------------------------------------------------
// Kernel 1: point->gt matching + sigmoid sortable key + 12-bit histogram.
// ---------------------------------------------------------------------------
__global__ __launch_bounds__(256)
void match_key_kernel(const float* __restrict__ points,
                      const float* __restrict__ gt,
                      const float* __restrict__ logits,
                      float* __restrict__ out_match,
                      u32* __restrict__ keys,
                      u32* __restrict__ ghist) {
#pragma clang fp contract(off)
    __shared__ float bx1[N_GT], by1[N_GT], bx2[N_GT], by2[N_GT], ar[N_GT];
    const int b = blockIdx.y;
    const int p = blockIdx.x * blockDim.x + threadIdx.x;

    for (int j = threadIdx.x; j < N_GT; j += blockDim.x) {
        float x1 = gt[(b * N_GT + j) * 4 + 0];
        float y1 = gt[(b * N_GT + j) * 4 + 1];
        float x2 = gt[(b * N_GT + j) * 4 + 2];
        float y2 = gt[(b * N_GT + j) * 4 + 3];
        bx1[j] = x1; by1[j] = y1; bx2[j] = x2; by2[j] = y2;
        ar[j] = (x2 - x1) * (y2 - y1);
    }
    __syncthreads();
    if (p >= N_POINTS) return;

    const float px = points[p * 2 + 0];
    const float py = points[p * 2 + 1];
    const float BIGF = 2147483648.0f;   // float32(2^31-1) rounds to 2^31
    float best = BIGF;
    int bi = -1;
#pragma unroll 4
    for (int j = 0; j < N_GT; ++j) {
        bool inside = (px >= bx1[j]) && (px <= bx2[j]) &&
                      (py >= by1[j]) && (py <= by2[j]);
        float cost = inside ? ar[j] : BIGF;
        if (cost < best) { best = cost; bi = j; }   // strict < = first-occurrence
    }
    out_match[b * N_POINTS + p] = (float)bi;

    float lg = logits[b * N_POINTS + p];
    float s = 1.0f / (1.0f + expf(-lg));
    u32 u = __float_as_uint(s);
    u32 key = (u & 0x80000000u) ? ~u : (u | 0x80000000u);
    keys[b * N_POINTS + p] = key;

    int seg = b * NLEV + level_of(p);
    atomicAdd(&ghist[seg * NBIN + (key >> 20)], 1u);
}

// ---------------------------------------------------------------------------
// Kernel 2: per-segment threshold select from histogram (one wave per segment).
// ---------------------------------------------------------------------------
__global__ __launch_bounds__(64)
void select_kernel(const u32* __restrict__ ghist, u32* __restrict__ params) {
    const int seg = blockIdx.x;            // b*5 + l
    const int l = seg % NLEV;
    const u32 K = (u32)k_of(l);
    const u32* h = ghist + seg * NBIN;
    const int lane = threadIdx.x;

    u32 S = 0;
#pragma unroll 8
    for (int i = 0; i < 64; ++i) S += h[lane * 64 + i];
    u32 acc = S;
#pragma unroll
    for (int off = 1; off < 64; off <<= 1) {
        u32 v = (u32)__shfl_down((int)acc, off);
        if (lane + off < 64) acc += v;
    }
    u32 sfxAfter = acc - S;
    bool hit = (sfxAfter < K) && (sfxAfter + S >= K);
    u64 bal = __ballot(hit);
    int Lg = (int)__builtin_ctzll(bal);
    u32 sfxG = (u32)__shfl((int)sfxAfter, Lg);

    u32 v = h[Lg * 64 + lane];
    u32 acc2 = v;
#pragma unroll
    for (int off = 1; off < 64; off <<= 1) {
        u32 t = (u32)__shfl_down((int)acc2, off);
        if (lane + off < 64) acc2 += t;
    }
    u32 sfx2 = sfxG + acc2 - v;
    bool hit2 = (sfx2 < K) && (sfx2 + v >= K);
    if (hit2) {
        params[seg * 2 + 0] = (u32)(Lg * 64 + lane);  // T
        params[seg * 2 + 1] = K - sfx2;               // kk within bin T
    }
}

// ---------------------------------------------------------------------------
// Kernel 3: one-pass compact with wave-aggregated atomics (R4 win).
// ---------------------------------------------------------------------------
__global__ __launch_bounds__(256)
void compact_kernel(const u32* __restrict__ keys,
                    const u32* __restrict__ params,
                    u32* __restrict__ cnt,
                    u64* __restrict__ defK,
                    u64* __restrict__ tieK) {
    const int idx = blockIdx.x * 256 + threadIdx.x;
    const bool active = idx < BATCH * N_POINTS;
    int b = 0, seg = 0;
    bool isDef = false, isTie = false;
    u64 k50 = 0;
    if (active) {
        b = idx / N_POINTS;
        int p = idx - b * N_POINTS;
        u32 key = keys[idx];
        int l = level_of(p);
        seg = b * NLEV + l;
        u32 T = params[seg * 2 + 0];
        u32 digit = key >> 20;
        int idxl = p - loff_of(l);
        k50 = ((u64)key << 18) | ((u64)(7 - l) << 15) | (u64)(32767 - idxl);
        isDef = digit > T;
        isTie = digit == T;
    }
    const int lane = threadIdx.x & 63;
    const u64 below = (lane == 0) ? 0ull : (~0ull >> (64 - lane));

    u64 defMask = __ballot(isDef);
    while (defMask) {
        int leader = (int)__builtin_ctzll(defMask);
        int bb = __shfl(b, leader);
        u64 grp = __ballot(isDef && (b == bb));
        u32 base = 0;
        if (lane == leader)
            base = atomicAdd(&cnt[bb], (u32)__builtin_popcountll(grp));
        base = (u32)__shfl((int)base, leader);
        if (isDef && (b == bb)) {
            u32 pos = base + (u32)__builtin_popcountll(grp & below);
            defK[bb * 3584 + pos] = k50;
        }
        defMask &= ~grp;
    }
    u64 tieMask = __ballot(isTie);
    while (tieMask) {
        int leader = (int)__builtin_ctzll(tieMask);
        int sg = __shfl(seg, leader);
        u64 grp = __ballot(isTie && (seg == sg));
        u32 base = 0;
        if (lane == leader)
            base = atomicAdd(&cnt[8 + sg], (u32)__builtin_popcountll(grp));
        base = (u32)__shfl((int)base, leader);
        if (isTie && (seg == sg)) {
            u32 pos = base + (u32)__builtin_popcountll(grp & below);
            if (pos < TIE_CAP) tieK[sg * TIE_CAP + pos] = k50;
        }
        tieMask &= ~grp;
    }
}

// ---------------------------------------------------------------------------
// Kernel 4: per-image: resolve ties, bitonic-sort 3500 keys (pad 4096) in LDS,
// decode boxes into sorted candidate arrays. 1024 threads (R6: was 512 —
// halves per-thread bitonic work per barrier pass).
// ---------------------------------------------------------------------------
#define SORT_T 1024
__global__ __launch_bounds__(SORT_T)
void sortimg_kernel(const u32* __restrict__ params,
                    const u32* __restrict__ cnt,
                    const u64* __restrict__ defK,
                    const u64* __restrict__ tieK,
                    const float* __restrict__ reg,
                    const float* __restrict__ points,
                    float* __restrict__ sboxes,
                    float* __restrict__ sscores) {
#pragma clang fp contract(off)
    __shared__ u64 sk[4096];
    __shared__ u64 tb[TIE_CAP];
    __shared__ int s_base;
    const int b = blockIdx.x;
    const int tid = threadIdx.x;

    int nd = (int)cnt[b];
    for (int i = tid; i < nd; i += SORT_T) sk[i] = defK[b * 3584 + i];
    if (tid == 0) s_base = nd;
    __syncthreads();

    for (int s = 0; s < NLEV; ++s) {
        int seg = b * NLEV + s;
        int t = (int)cnt[8 + seg];
        if (t > TIE_CAP) t = TIE_CAP;
        int kk = (int)params[seg * 2 + 1];
        for (int i = tid; i < t; i += SORT_T) tb[i] = tieK[seg * TIE_CAP + i];
        __syncthreads();
        int base = s_base;
        for (int j = tid; j < t; j += SORT_T) {
            u64 kj = tb[j];
            int r = 0;
            for (int i = 0; i < t; ++i) r += (tb[i] > kj) ? 1 : 0;
            if (r < kk) sk[base + r] = kj;       // unique ranks -> exact fill
        }
        __syncthreads();
        if (tid == 0) s_base = base + kk;
        __syncthreads();
    }
    const int total = s_base;                    // == 3500 by construction
    for (int i = tid; i < 4096; i += SORT_T)
        if (i >= total) sk[i] = 0ull;
    __syncthreads();

    // bitonic sort, descending (keys unique; zeros sink)
    for (int k = 2; k <= 4096; k <<= 1) {
        for (int j = k >> 1; j > 0; j >>= 1) {
            for (int i = tid; i < 4096; i += SORT_T) {
                int ixj = i ^ j;
                if (ixj > i) {
                    u64 a = sk[i], c = sk[ixj];
                    bool desc = ((i & k) == 0);
                    if (desc ? (a < c) : (a > c)) { sk[i] = c; sk[ixj] = a; }
                }
            }
            __syncthreads();
        }
    }

    // decode + write sorted candidates
    for (int r = tid; r < NCAND; r += SORT_T) {
        float x1 = 0.f, y1 = 0.f, x2 = 0.f, y2 = 0.f, sc = 0.f;
        if (r < total) {
            u64 k50 = sk[r];
            int lowb = (int)(k50 & 0x3FFFFull);
            int l = 7 - (lowb >> 15);
            int idxl = 32767 - (lowb & 32767);
            int p = loff_of(l) + idxl;
            u32 key32 = (u32)(k50 >> 18);
            sc = __uint_as_float(key32 ^ 0x80000000u);
            int gp = b * N_POINTS + p;
            float l_ = reg[gp * 4 + 0] * IMG;
            float t_ = reg[gp * 4 + 1] * IMG;
            float r_ = reg[gp * 4 + 2] * IMG;
            float bb = reg[gp * 4 + 3] * IMG;
            float px = points[p * 2 + 0];
            float py = points[p * 2 + 1];
            x1 = fminf(fmaxf(px - l_, 0.0f), IMG);
            y1 = fminf(fmaxf(py - t_, 0.0f), IMG);
            x2 = fminf(fmaxf(px + r_, 0.0f), IMG);
            y2 = fminf(fmaxf(py + bb, 0.0f), IMG);
        }
        int slot = b * NCAND + r;
        sboxes[slot * 4 + 0] = x1;
        sboxes[slot * 4 + 1] = y1;
        sboxes[slot * 4 + 2] = x2;
        sboxes[slot * 4 + 3] = y2;
        sscores[slot] = sc;
    }
}

// ---------------------------------------------------------------------------
// Kernel 5: suppression-mask matrix (R4-verified), packed upper triangle.
// R6: grid 128x8 = 1024 blocks (was 256). LDS 56 KB allows 2 blocks/CU ->
// 8 waves/CU (was 4) to hide LDS/ballot latency (R4: VALUBusy 34%).
// ---------------------------------------------------------------------------
__global__ __launch_bounds__(256)
void mask_kernel(const float* __restrict__ sboxes,
                 const float* __restrict__ sscores,
                 u64* __restrict__ mask) {
#pragma clang fp contract(off)
    __shared__ float4 sb[3520];
    const int b = blockIdx.y;
    const int tid = threadIdx.x;
    const float4* gb = (const float4*)sboxes + b * NCAND;
    for (int i = tid; i < 3520; i += 256)
        sb[i] = (i < NCAND) ? gb[i] : make_float4(0.f, 0.f, 0.f, 0.f);
    __syncthreads();

    const int lane = tid & 63;
    const int wv = tid >> 6;
    u64* mrow = mask + (size_t)b * MASK_STRIDE;
    const float* ssc = sscores + b * NCAND;
    const int stride = gridDim.x * 4;

    for (int c = blockIdx.x * 4 + wv; c < NCAND; c += stride) {
        if (!(ssc[c] > SCORE_TH)) continue;          // wave-uniform
        float4 bc = sb[c];
        float a1 = (bc.z - bc.x) * (bc.w - bc.y);
        int g = c >> 6;
        int off = mask_off(c);
        for (int w = g; w < 55; ++w) {
            float4 bj = sb[(w << 6) + lane];
            float x1 = fmaxf(bc.x, bj.x);
            float y1 = fmaxf(bc.y, bj.y);
            float x2 = fminf(bc.z, bj.z);
            float y2 = fminf(bc.w, bj.w);
            float inter = fmaxf(x2 - x1, 0.f) * fmaxf(y2 - y1, 0.f);
            float a2 = (bj.z - bj.x) * (bj.w - bj.y);
            float iou = inter / (a1 + a2 - inter + 1e-9f);  // IEEE div
            u64 bits = __ballot(iou > NMS_TH);
            if (lane == 0) mrow[off + (w - g)] = bits;
        }
    }
}

// ---------------------------------------------------------------------------
// Kernel 6: sorted-order NMS scan (R4-verified), two-phase per word.
// ---------------------------------------------------------------------------
__global__ __launch_bounds__(256)
void scan_kernel(const float* __restrict__ sboxes,
                 const float* __restrict__ sscores,
                 const u64* __restrict__ mask,
                 float* __restrict__ out) {
#pragma clang fp contract(off)
    __shared__ float4 sb[3520];
    __shared__ float sl[3520];
    const int b = blockIdx.x;
    const int tid = threadIdx.x;
    const float4* gb = (const float4*)sboxes + b * NCAND;
    const float* gs = sscores + b * NCAND;
    for (int i = tid; i < 3520; i += 256) {
        sb[i] = (i < NCAND) ? gb[i] : make_float4(0.f, 0.f, 0.f, 0.f);
        sl[i] = (i < NCAND) ? gs[i] : 0.f;
    }
    __syncthreads();
    if (tid >= 64) return;               // single wave scans

    const int lane = tid;
    const u64* mrow = mask + (size_t)b * MASK_STRIDE;

    u64 m = 0ull;
    for (int w = 0; w < 55; ++w) {
        int c = (w << 6) + lane;
        bool bad = !((c < NCAND) && (sl[c] > SCORE_TH));
        u64 bal = __ballot(bad);
        if (lane == w) m = bal;
    }

    float* ob = out + OUT_BOXES  + b * MAX_DET * 4;
    float* os = out + OUT_SCORES + b * MAX_DET;
    float* ol = out + OUT_LABELS + b * MAX_DET;
    float* ov = out + OUT_VALID  + b * MAX_DET;

    int kept = 0;
    for (int w = 0; w < 55 && kept < MAX_DET; ++w) {
        u64 cur = __shfl(m, w);
        if (cur == ~0ull) continue;
        const int wbase = (w << 6);
        const float4 bj = sb[wbase + lane];        // fixed per word
        const float a2j = (bj.z - bj.x) * (bj.w - bj.y);
        u64 km = 0ull;

        // phase 1: keeps via ballots (intra-word suppression recomputed in-wave)
        while (kept < MAX_DET) {
            u64 avail = ~cur;
            if (avail == 0ull) break;
            int t = (int)__builtin_ctzll(avail);
            int c = wbase + t;
            float4 bc = sb[c];
            float a1 = (bc.z - bc.x) * (bc.w - bc.y);
            float x1 = fmaxf(bc.x, bj.x);
            float y1 = fmaxf(bc.y, bj.y);
            float x2 = fminf(bc.z, bj.z);
            float y2 = fminf(bc.w, bj.w);
            float inter = fmaxf(x2 - x1, 0.f) * fmaxf(y2 - y1, 0.f);
            float iou = inter / (a1 + a2j - inter + 1e-9f);
            cur |= __ballot(iou > NMS_TH) | (1ull << t);
            km |= 1ull << t;
            if (lane == 0) {
                ob[kept * 4 + 0] = bc.x;
                ob[kept * 4 + 1] = bc.y;
                ob[kept * 4 + 2] = bc.z;
                ob[kept * 4 + 3] = bc.w;
                os[kept] = sl[c];
                ol[kept] = 0.0f;
                ov[kept] = 1.0f;
            }
            kept++;
        }

        // phase 2: OR kept rows into future words, 8 loads per wait
        if (km) {
            const bool lr = (lane >= w && lane < 55);
            const int lo = lane - w;
            u64 acc = 0ull;
            while (km) {
#define POPBIT(tn) int tn = -1; if (km) { tn = (int)__builtin_ctzll(km); km &= km - 1ull; }
                POPBIT(t0) POPBIT(t1) POPBIT(t2) POPBIT(t3)
                POPBIT(t4) POPBIT(t5) POPBIT(t6) POPBIT(t7)
#undef POPBIT
                u64 v0 = 0, v1 = 0, v2 = 0, v3 = 0, v4 = 0, v5 = 0, v6 = 0, v7 = 0;
                if (lr) {
                    v0 = mrow[mask_off(wbase + t0) + lo];
                    if (t1 >= 0) v1 = mrow[mask_off(wbase + t1) + lo];
                    if (t2 >= 0) v2 = mrow[mask_off(wbase + t2) + lo];
                    if (t3 >= 0) v3 = mrow[mask_off(wbase + t3) + lo];
                    if (t4 >= 0) v4 = mrow[mask_off(wbase + t4) + lo];
                    if (t5 >= 0) v5 = mrow[mask_off(wbase + t5) + lo];
                    if (t6 >= 0) v6 = mrow[mask_off(wbase + t6) + lo];
                    if (t7 >= 0) v7 = mrow[mask_off(wbase + t7) + lo];
                }
                acc |= ((v0 | v1) | (v2 | v3)) | ((v4 | v5) | (v6 | v7));
            }
            m |= acc;
        }
    }
    for (int k = kept + lane; k < MAX_DET; k += 64) {
        ob[k * 4 + 0] = 0.f; ob[k * 4 + 1] = 0.f;
        ob[k * 4 + 2] = 0.f; ob[k * 4 + 3] = 0.f;
        os[k] = 0.f; ol[k] = -1.f; ov[k] = 0.f;
    }
}

// ---------------------------------------------------------------------------
extern "C" void kernel_launch(void* const* d_in, const int* in_sizes, int n_in,
                              void* d_out, int out_size, void* d_ws, size_t ws_size,
                              hipStream_t stream) {
    const float* points = (const float*)d_in[0];
    const float* gt     = (const float*)d_in[1];
    const float* logits = (const float*)d_in[2];
    const float* reg    = (const float*)d_in[3];
    float* out = (float*)d_out;

    u32* keys   = (u32*)((char*)d_ws + WS_KEYS);
    u32* ghist  = (u32*)((char*)d_ws + WS_GHIST);
    u32* params = (u32*)((char*)d_ws + WS_PARAMS);
    u32* cnt    = (u32*)((char*)d_ws + WS_CNT);
    u64* defK   = (u64*)((char*)d_ws + WS_DEFK);
    u64* tieK   = (u64*)((char*)d_ws + WS_TIEK);
    float* sboxes  = (float*)((char*)d_ws + WS_SBOX);
    float* sscores = (float*)((char*)d_ws + WS_SSC);
    u64* mask   = (u64*)((char*)d_ws + WS_MASK);

    zero_kernel<<<256, 256, 0, stream>>>(ghist);

    dim3 g1((N_POINTS + 255) / 256, BATCH);
    match_key_kernel<<<g1, 256, 0, stream>>>(points, gt, logits,
                                             out + OUT_MATCH, keys, ghist);

    select_kernel<<<BATCH * NLEV, 64, 0, stream>>>(ghist, params);

    compact_kernel<<<(BATCH * N_POINTS + 255) / 256, 256, 0, stream>>>(
        keys, params, cnt, defK, tieK);

    sortimg_kernel<<<BATCH, SORT_T, 0, stream>>>(params, cnt, defK, tieK,
                                                 reg, points, sboxes, sscores);

    dim3 g5(128, BATCH);   // 1024 blocks: 2 blocks/CU (LDS-capped) -> 8 waves/CU
    mask_kernel<<<g5, 256, 0, stream>>>(sboxes, sscores, mask);

    scan_kernel<<<BATCH, 256, 0, stream>>>(sboxes, sscores, mask, out);
}

// Round 7
// 458.250 us; speedup vs baseline: 1.3636x; 1.0308x over previous
//
#include <hip/hip_runtime.h>
#include <stdint.h>

// Problem constants
#define N_POINTS   34100
#define BATCH      8
#define N_GT       200
#define NLEV       5
#define NCAND      3500
#define MAX_DET    300
#define SCORE_TH   0.05f
#define NMS_TH     0.5f
#define IMG        1280.0f
#define TIE_CAP    2048
#define NBIN       4096
// Exact threshold: RN(inter/denom) > 0.5  <=>  inter > (0.5+2^-25)*denom
// (RN monotone; x = 0.5+2^-25 is the tie midpoint, ties-to-even rounds DOWN to
//  0.5; f64 product of 24-bit * 25-bit mantissas is exact)
#define MTH 0.50000002980232238769531250

// Output layout (float32 flat, reference return order)
#define OUT_MATCH  0        // 8*34100
#define OUT_BOXES  272800   // 8*300*4
#define OUT_SCORES 282400   // 8*300
#define OUT_LABELS 284800   // 8*300
#define OUT_VALID  287200   // 8*300

// Workspace layout (bytes)
#define WS_KEYS    0              // u32[8*34100]   = 1,091,200
#define WS_GHIST   1091200        // u32[40*4096]   =   655,360
#define WS_PARAMS  1746560        // u32[40*2] (T,kk), pad 640
#define WS_CNT     1747200        // u32[64]
#define WS_DEFK    1747456        // u64[8*3584]    =   229,376
#define WS_TIEK    1976832        // u64[40*2048]   =   655,360
#define WS_SBOX    2632192        // float4[8*3500] =   448,000
#define WS_SSC     3080192        // float[8*3500]  =   112,000
#define WS_MASK    3192192        // u64[8*98560]   = 6,307,840
#define MASK_STRIDE 98560         // words per image (packed triangle, padded)

typedef unsigned long long u64;
typedef uint32_t u32;

// Packed upper-triangle row offset: row c stores words (c>>6)..54
__device__ __forceinline__ int mask_off(int c) {
    int g = c >> 6;
    return 64 * (55 * g - (g * (g - 1)) / 2) + (c - (g << 6)) * (55 - g);
}

__device__ __forceinline__ int level_of(int p) {
    return (p < 25600) ? 0 : (p < 32000) ? 1 : (p < 33600) ? 2 : (p < 34000) ? 3 : 4;
}
__device__ __forceinline__ int loff_of(int l) {
    return (l == 0) ? 0 : (l == 1) ? 25600 : (l == 2) ? 32000 : (l == 3) ? 33600 : 34000;
}
__device__ __forceinline__ int k_of(int l) {
    return (l == 0) ? 1000 : (l == 1) ? 1000 : (l == 2) ? 1000 : (l == 3) ? 400 : 100;
}
__device__ __forceinline__ u64 readlane64(u64 v, int t) {
    u32 lo = (u32)__builtin_amdgcn_readlane((int)(u32)v, t);
    u32 hi = (u32)__builtin_amdgcn_readlane((int)(u32)(v >> 32), t);
    return ((u64)hi << 32) | lo;
}
__device__ __forceinline__ float readlanef(float v, int t) {
    return __int_as_float(__builtin_amdgcn_readlane(__float_as_int(v), t));
}

// ---------------------------------------------------------------------------
// Kernel 0: zero histograms + counters
// ---------------------------------------------------------------------------
__global__ __launch_bounds__(256)
void zero_kernel(u32* __restrict__ g) {
    const int n = (WS_CNT + 256 - WS_GHIST) / 4;
    for (int i = blockIdx.x * 256 + threadIdx.x; i < n; i += gridDim.x * 256)
        g[i] = 0u;
}

// ---------------------------------------------------------------------------
// Kernel 1: point->gt matching + sigmoid key + histogram.
// R7: 4 points/thread — amortizes the 200x5 LDS broadcast reads (R1-R6 did
// 1000 ds_read_b32 per point -> LDS-issue bound ~138 us).
// ---------------------------------------------------------------------------
#define MPT 4
__global__ __launch_bounds__(256)
void match_key_kernel(const float* __restrict__ points,
                      const float* __restrict__ gt,
                      const float* __restrict__ logits,
                      float* __restrict__ out_match,
                      u32* __restrict__ keys,
                      u32* __restrict__ ghist) {
#pragma clang fp contract(off)
    __shared__ float bx1[N_GT], by1[N_GT], bx2[N_GT], by2[N_GT], ar[N_GT];
    const int b = blockIdx.y;
    const int base = blockIdx.x * (256 * MPT) + threadIdx.x;

    for (int j = threadIdx.x; j < N_GT; j += 256) {
        float x1 = gt[(b * N_GT + j) * 4 + 0];
        float y1 = gt[(b * N_GT + j) * 4 + 1];
        float x2 = gt[(b * N_GT + j) * 4 + 2];
        float y2 = gt[(b * N_GT + j) * 4 + 3];
        bx1[j] = x1; by1[j] = y1; bx2[j] = x2; by2[j] = y2;
        ar[j] = (x2 - x1) * (y2 - y1);
    }
    __syncthreads();

    const float BIGF = 2147483648.0f;   // float32(2^31-1) rounds to 2^31
    float px[MPT], py[MPT], best[MPT];
    int bi[MPT];
#pragma unroll
    for (int k = 0; k < MPT; ++k) {
        int p = base + k * 256;
        bool v = p < N_POINTS;
        int pc = v ? p : 0;
        px[k] = points[pc * 2 + 0];
        py[k] = points[pc * 2 + 1];
        best[k] = BIGF; bi[k] = -1;
    }
    for (int j = 0; j < N_GT; ++j) {
        float x1 = bx1[j], y1 = by1[j], x2 = bx2[j], y2 = by2[j], a = ar[j];
#pragma unroll
        for (int k = 0; k < MPT; ++k) {
            bool inside = (px[k] >= x1) && (px[k] <= x2) &&
                          (py[k] >= y1) && (py[k] <= y2);
            float cost = inside ? a : BIGF;
            if (cost < best[k]) { best[k] = cost; bi[k] = j; }   // strict <
        }
    }
#pragma unroll
    for (int k = 0; k < MPT; ++k) {
        int p = base + k * 256;
        if (p >= N_POINTS) continue;
        out_match[b * N_POINTS + p] = (float)bi[k];
        float lg = logits[b * N_POINTS + p];
        float s = 1.0f / (1.0f + expf(-lg));
        u32 u = __float_as_uint(s);
        u32 key = (u & 0x80000000u) ? ~u : (u | 0x80000000u);
        keys[b * N_POINTS + p] = key;
        int seg = b * NLEV + level_of(p);
        atomicAdd(&ghist[seg * NBIN + ((key >> 19) & 4095u)], 1u);
    }
}

// ---------------------------------------------------------------------------
// Kernel 2: per-segment threshold select from histogram (one wave/segment).
// ---------------------------------------------------------------------------
__global__ __launch_bounds__(64)
void select_kernel(const u32* __restrict__ ghist, u32* __restrict__ params) {
    const int seg = blockIdx.x;
    const int l = seg % NLEV;
    const u32 K = (u32)k_of(l);
    const u32* h = ghist + seg * NBIN;
    const int lane = threadIdx.x;

    u32 S = 0;
#pragma unroll 8
    for (int i = 0; i < 64; ++i) S += h[lane * 64 + i];
    u32 acc = S;
#pragma unroll
    for (int off = 1; off < 64; off <<= 1) {
        u32 v = (u32)__shfl_down((int)acc, off);
        if (lane + off < 64) acc += v;
    }
    u32 sfxAfter = acc - S;
    bool hit = (sfxAfter < K) && (sfxAfter + S >= K);
    u64 bal = __ballot(hit);
    int Lg = (int)__builtin_ctzll(bal);
    u32 sfxG = (u32)__shfl((int)sfxAfter, Lg);

    u32 v = h[Lg * 64 + lane];
    u32 acc2 = v;
#pragma unroll
    for (int off = 1; off < 64; off <<= 1) {
        u32 t = (u32)__shfl_down((int)acc2, off);
        if (lane + off < 64) acc2 += t;
    }
    u32 sfx2 = sfxG + acc2 - v;
    bool hit2 = (sfx2 < K) && (sfx2 + v >= K);
    if (hit2) {
        params[seg * 2 + 0] = (u32)(Lg * 64 + lane);  // T
        params[seg * 2 + 1] = K - sfx2;               // kk within bin T
    }
}

// ---------------------------------------------------------------------------
// Kernel 3: one-pass compact with wave-aggregated atomics (R4 win).
// ---------------------------------------------------------------------------
__global__ __launch_bounds__(256)
void compact_kernel(const u32* __restrict__ keys,
                    const u32* __restrict__ params,
                    u32* __restrict__ cnt,
                    u64* __restrict__ defK,
                    u64* __restrict__ tieK) {
    const int idx = blockIdx.x * 256 + threadIdx.x;
    const bool active = idx < BATCH * N_POINTS;
    int b = 0, seg = 0;
    bool isDef = false, isTie = false;
    u64 k50 = 0;
    if (active) {
        b = idx / N_POINTS;
        int p = idx - b * N_POINTS;
        u32 key = keys[idx];
        int l = level_of(p);
        seg = b * NLEV + l;
        u32 T = params[seg * 2 + 0];
        u32 digit = (key >> 19) & 4095u;
        int idxl = p - loff_of(l);
        k50 = ((u64)key << 18) | ((u64)(7 - l) << 15) | (u64)(32767 - idxl);
        isDef = digit > T;
        isTie = digit == T;
    }
    const int lane = threadIdx.x & 63;
    const u64 below = (lane == 0) ? 0ull : (~0ull >> (64 - lane));

    u64 defMask = __ballot(isDef);
    while (defMask) {
        int leader = (int)__builtin_ctzll(defMask);
        int bb = __shfl(b, leader);
        u64 grp = __ballot(isDef && (b == bb));
        u32 base = 0;
        if (lane == leader)
            base = atomicAdd(&cnt[bb], (u32)__builtin_popcountll(grp));
        base = (u32)__shfl((int)base, leader);
        if (isDef && (b == bb)) {
            u32 pos = base + (u32)__builtin_popcountll(grp & below);
            defK[bb * 3584 + pos] = k50;
        }
        defMask &= ~grp;
    }
    u64 tieMask = __ballot(isTie);
    while (tieMask) {
        int leader = (int)__builtin_ctzll(tieMask);
        int sg = __shfl(seg, leader);
        u64 grp = __ballot(isTie && (seg == sg));
        u32 base = 0;
        if (lane == leader)
            base = atomicAdd(&cnt[8 + sg], (u32)__builtin_popcountll(grp));
        base = (u32)__shfl((int)base, leader);
        if (isTie && (seg == sg)) {
            u32 pos = base + (u32)__builtin_popcountll(grp & below);
            if (pos < TIE_CAP) tieK[sg * TIE_CAP + pos] = k50;
        }
        tieMask &= ~grp;
    }
}

// ---------------------------------------------------------------------------
// Kernel 4: per-image: resolve ties, bitonic-sort 3500 keys (pad 4096) in LDS,
// decode boxes into sorted candidate arrays.
// ---------------------------------------------------------------------------
#define SORT_T 1024
__global__ __launch_bounds__(SORT_T)
void sortimg_kernel(const u32* __restrict__ params,
                    const u32* __restrict__ cnt,
                    const u64* __restrict__ defK,
                    const u64* __restrict__ tieK,
                    const float* __restrict__ reg,
                    const float* __restrict__ points,
                    float* __restrict__ sboxes,
                    float* __restrict__ sscores) {
#pragma clang fp contract(off)
    __shared__ u64 sk[4096];
    __shared__ u64 tb[TIE_CAP];
    __shared__ int s_base;
    const int b = blockIdx.x;
    const int tid = threadIdx.x;

    int nd = (int)cnt[b];
    for (int i = tid; i < nd; i += SORT_T) sk[i] = defK[b * 3584 + i];
    if (tid == 0) s_base = nd;
    __syncthreads();

    for (int s = 0; s < NLEV; ++s) {
        int seg = b * NLEV + s;
        int t = (int)cnt[8 + seg];
        if (t > TIE_CAP) t = TIE_CAP;
        int kk = (int)params[seg * 2 + 1];
        for (int i = tid; i < t; i += SORT_T) tb[i] = tieK[seg * TIE_CAP + i];
        __syncthreads();
        int base = s_base;
        for (int j = tid; j < t; j += SORT_T) {
            u64 kj = tb[j];
            int r = 0;
            for (int i = 0; i < t; ++i) r += (tb[i] > kj) ? 1 : 0;
            if (r < kk) sk[base + r] = kj;       // unique ranks -> exact fill
        }
        __syncthreads();
        if (tid == 0) s_base = base + kk;
        __syncthreads();
    }
    const int total = s_base;                    // == 3500 by construction
    for (int i = tid; i < 4096; i += SORT_T)
        if (i >= total) sk[i] = 0ull;
    __syncthreads();

    for (int k = 2; k <= 4096; k <<= 1) {
        for (int j = k >> 1; j > 0; j >>= 1) {
            for (int i = tid; i < 4096; i += SORT_T) {
                int ixj = i ^ j;
                if (ixj > i) {
                    u64 a = sk[i], c = sk[ixj];
                    bool desc = ((i & k) == 0);
                    if (desc ? (a < c) : (a > c)) { sk[i] = c; sk[ixj] = a; }
                }
            }
            __syncthreads();
        }
    }

    for (int r = tid; r < NCAND; r += SORT_T) {
        float x1 = 0.f, y1 = 0.f, x2 = 0.f, y2 = 0.f, sc = 0.f;
        if (r < total) {
            u64 k50 = sk[r];
            int lowb = (int)(k50 & 0x3FFFFull);
            int l = 7 - (lowb >> 15);
            int idxl = 32767 - (lowb & 32767);
            int p = loff_of(l) + idxl;
            u32 key32 = (u32)(k50 >> 18);
            sc = __uint_as_float(key32 ^ 0x80000000u);
            int gp = b * N_POINTS + p;
            float l_ = reg[gp * 4 + 0] * IMG;
            float t_ = reg[gp * 4 + 1] * IMG;
            float r_ = reg[gp * 4 + 2] * IMG;
            float bb = reg[gp * 4 + 3] * IMG;
            float px = points[p * 2 + 0];
            float py = points[p * 2 + 1];
            x1 = fminf(fmaxf(px - l_, 0.0f), IMG);
            y1 = fminf(fmaxf(py - t_, 0.0f), IMG);
            x2 = fminf(fmaxf(px + r_, 0.0f), IMG);
            y2 = fminf(fmaxf(py + bb, 0.0f), IMG);
        }
        int slot = b * NCAND + r;
        sboxes[slot * 4 + 0] = x1;
        sboxes[slot * 4 + 1] = y1;
        sboxes[slot * 4 + 2] = x2;
        sboxes[slot * 4 + 3] = y2;
        sscores[slot] = sc;
    }
}

// ---------------------------------------------------------------------------
// Kernel 5: suppression-mask matrix. R7: LDS-free balanced restructure.
// Block (w, b, slice): lanes = word-w candidates (bj per lane, fixed);
// loop c over [0, (w+1)*64) strided by wave+slice; bc/score broadcast loads.
// Compare exactly without div: inter_f64 > (0.5+2^-25)*denom_f64.
// ---------------------------------------------------------------------------
__global__ __launch_bounds__(256)
void mask_kernel(const float* __restrict__ sboxes,
                 const float* __restrict__ sscores,
                 u64* __restrict__ mask) {
#pragma clang fp contract(off)
    const int w = 54 - blockIdx.x;           // big blocks dispatched first
    const int b = blockIdx.y;
    const int slice = blockIdx.z;            // 0..3
    const int lane = threadIdx.x & 63;
    const int wv = threadIdx.x >> 6;         // 0..3

    const float4* gb = (const float4*)sboxes + b * NCAND;
    const float* gs = sscores + b * NCAND;
    u64* mout = mask + (size_t)b * MASK_STRIDE;

    int cj = (w << 6) + lane;
    float4 bj = (cj < NCAND) ? gb[cj] : make_float4(0.f, 0.f, 0.f, 0.f);
    const float a2 = (bj.z - bj.x) * (bj.w - bj.y);

    const int cmax = (NCAND < ((w + 1) << 6)) ? NCAND : ((w + 1) << 6);
    for (int c = slice * 4 + wv; c < cmax; c += 16) {
        float sc_ = gs[c];                    // broadcast
        if (!(sc_ > SCORE_TH)) continue;      // wave-uniform
        float4 bc = gb[c];                    // broadcast
        float a1 = (bc.z - bc.x) * (bc.w - bc.y);
        float x1 = fmaxf(bc.x, bj.x);
        float y1 = fmaxf(bc.y, bj.y);
        float x2 = fminf(bc.z, bj.z);
        float y2 = fminf(bc.w, bj.w);
        float inter = fmaxf(x2 - x1, 0.f) * fmaxf(y2 - y1, 0.f);
        float denom = a1 + a2 - inter + 1e-9f;     // same assoc as reference
        u64 bits = __ballot((double)inter > MTH * (double)denom);
        if (lane == 0) mout[mask_off(c) + (w - (c >> 6))] = bits;
    }
}

// ---------------------------------------------------------------------------
// Kernel 6: sorted-order NMS scan. R7: per-keep chain = s_ff1 + v_readlane
// (intra-word suppression bits come from the precomputed mask rows held in
// per-lane VGPRs; no LDS read / IoU / div / ballot on the chain).
// ---------------------------------------------------------------------------
__global__ __launch_bounds__(64)
void scan_kernel(const float* __restrict__ sboxes,
                 const float* __restrict__ sscores,
                 const u64* __restrict__ mask,
                 float* __restrict__ out) {
    const int b = blockIdx.x;
    const int lane = threadIdx.x;            // 64 threads = 1 wave
    const float4* gb = (const float4*)sboxes + b * NCAND;
    const float* gs = sscores + b * NCAND;
    const u64* mrow = mask + (size_t)b * MASK_STRIDE;

    float* ob = out + OUT_BOXES  + b * MAX_DET * 4;
    float* os = out + OUT_SCORES + b * MAX_DET;
    float* ol = out + OUT_LABELS + b * MAX_DET;
    float* ov = out + OUT_VALID  + b * MAX_DET;

    u64 m = 0ull;                            // lane f owns future-word f
    // preload word 0: intra rows + boxes + scores (per lane)
    int c0 = lane;
    u64 rowN = mrow[mask_off(c0)];
    float4 bjN = gb[c0];
    float sjN = gs[c0];

    int kept = 0;
    for (int w = 0; w < 55; ++w) {
        const int wbase = w << 6;
        const u64 row = rowN;
        const float4 bj = bjN;
        const float sj = sjN;
        // prefetch next word (consumed next iteration)
        if (w < 54) {
            int cn = wbase + 64 + lane;
            int cc = (cn < NCAND) ? cn : (NCAND - 1);
            rowN = mrow[mask_off(cc)];
            bjN = gb[cc];
            float s = gs[cc];
            sjN = (cn < NCAND) ? s : 0.f;
        }
        int c = wbase + lane;
        u64 bad = __ballot(!((c < NCAND) && (sj > SCORE_TH)));
        u64 cur = readlane64(m, w) | bad;
        u64 km = 0ull;
        // phase 1: serial keeps — uniform scalar chain, ~30 cyc/keep
        while (kept < MAX_DET) {
            u64 avail = ~cur;
            if (avail == 0ull) break;
            int t = (int)__builtin_ctzll(avail);       // uniform
            u64 r = readlane64(row, t);                // keep t's intra bits
            cur |= r | (1ull << t);
            km |= 1ull << t;
            float bx = readlanef(bj.x, t);
            float by = readlanef(bj.y, t);
            float bz = readlanef(bj.z, t);
            float bw = readlanef(bj.w, t);
            float sc = readlanef(sj, t);
            if (lane == 0) {
                ob[kept * 4 + 0] = bx;
                ob[kept * 4 + 1] = by;
                ob[kept * 4 + 2] = bz;
                ob[kept * 4 + 3] = bw;
                os[kept] = sc;
                ol[kept] = 0.0f;
                ov[kept] = 1.0f;
            }
            kept++;
        }
        // phase 2: OR kept rows into future words, 8 loads per wait
        if (km) {
            const bool lr = (lane >= w && lane < 55);
            const int lo = lane - w;
            u64 acc = 0ull;
            while (km) {
#define POPBIT(tn) int tn = -1; if (km) { tn = (int)__builtin_ctzll(km); km &= km - 1ull; }
                POPBIT(t0) POPBIT(t1) POPBIT(t2) POPBIT(t3)
                POPBIT(t4) POPBIT(t5) POPBIT(t6) POPBIT(t7)
#undef POPBIT
                u64 v0 = 0, v1 = 0, v2 = 0, v3 = 0, v4 = 0, v5 = 0, v6 = 0, v7 = 0;
                if (lr) {
                    v0 = mrow[mask_off(wbase + t0) + lo];
                    if (t1 >= 0) v1 = mrow[mask_off(wbase + t1) + lo];
                    if (t2 >= 0) v2 = mrow[mask_off(wbase + t2) + lo];
                    if (t3 >= 0) v3 = mrow[mask_off(wbase + t3) + lo];
                    if (t4 >= 0) v4 = mrow[mask_off(wbase + t4) + lo];
                    if (t5 >= 0) v5 = mrow[mask_off(wbase + t5) + lo];
                    if (t6 >= 0) v6 = mrow[mask_off(wbase + t6) + lo];
                    if (t7 >= 0) v7 = mrow[mask_off(wbase + t7) + lo];
                }
                acc |= ((v0 | v1) | (v2 | v3)) | ((v4 | v5) | (v6 | v7));
            }
            m |= acc;
        }
        if (kept >= MAX_DET) break;
    }
    for (int k = kept + lane; k < MAX_DET; k += 64) {
        ob[k * 4 + 0] = 0.f; ob[k * 4 + 1] = 0.f;
        ob[k * 4 + 2] = 0.f; ob[k * 4 + 3] = 0.f;
        os[k] = 0.f; ol[k] = -1.f; ov[k] = 0.f;
    }
}

// ---------------------------------------------------------------------------
extern "C" void kernel_launch(void* const* d_in, const int* in_sizes, int n_in,
                              void* d_out, int out_size, void* d_ws, size_t ws_size,
                              hipStream_t stream) {
    const float* points = (const float*)d_in[0];
    const float* gt     = (const float*)d_in[1];
    const float* logits = (const float*)d_in[2];
    const float* reg    = (const float*)d_in[3];
    float* out = (float*)d_out;

    u32* keys   = (u32*)((char*)d_ws + WS_KEYS);
    u32* ghist  = (u32*)((char*)d_ws + WS_GHIST);
    u32* params = (u32*)((char*)d_ws + WS_PARAMS);
    u32* cnt    = (u32*)((char*)d_ws + WS_CNT);
    u64* defK   = (u64*)((char*)d_ws + WS_DEFK);
    u64* tieK   = (u64*)((char*)d_ws + WS_TIEK);
    float* sboxes  = (float*)((char*)d_ws + WS_SBOX);
    float* sscores = (float*)((char*)d_ws + WS_SSC);
    u64* mask   = (u64*)((char*)d_ws + WS_MASK);

    zero_kernel<<<256, 256, 0, stream>>>(ghist);

    dim3 g1((N_POINTS + 256 * MPT - 1) / (256 * MPT), BATCH);
    match_key_kernel<<<g1, 256, 0, stream>>>(points, gt, logits,
                                             out + OUT_MATCH, keys, ghist);

    select_kernel<<<BATCH * NLEV, 64, 0, stream>>>(ghist, params);

    compact_kernel<<<(BATCH * N_POINTS + 255) / 256, 256, 0, stream>>>(
        keys, params, cnt, defK, tieK);

    sortimg_kernel<<<BATCH, SORT_T, 0, stream>>>(params, cnt, defK, tieK,
                                                 reg, points, sboxes, sscores);

    dim3 g5(55, BATCH, 4);
    mask_kernel<<<g5, 256, 0, stream>>>(sboxes, sscores, mask);

    scan_kernel<<<BATCH, 64, 0, stream>>>(sboxes, sscores, mask, out);
}

// Round 8
// 357.884 us; speedup vs baseline: 1.7460x; 1.2804x over previous
//
#include <hip/hip_runtime.h>
#include <stdint.h>

// Problem constants
#define N_POINTS   34100
#define BATCH      8
#define N_GT       200
#define NLEV       5
#define NCAND      3500
#define MAX_DET    300
#define SCORE_TH   0.05f
#define NMS_TH     0.5f
#define IMG        1280.0f
#define TIE_CAP    2048
#define NBIN       4096
// Exact threshold: RN(inter/denom) > 0.5  <=>  inter_f64 > (0.5+2^-25)*denom_f64
// (RN monotone; tie midpoint rounds to even = down to 0.5; 24x25-bit f64
//  product exact). Verified absmax 0 in R7.
#define MTH 0.50000002980232238769531250

// Output layout (float32 flat, reference return order)
#define OUT_MATCH  0        // 8*34100
#define OUT_BOXES  272800   // 8*300*4
#define OUT_SCORES 282400   // 8*300
#define OUT_LABELS 284800   // 8*300
#define OUT_VALID  287200   // 8*300

// Workspace layout (bytes)
#define WS_KEYS    0              // u32[8*34100]   = 1,091,200
#define WS_GHIST   1091200        // u32[40*4096]   =   655,360
#define WS_PARAMS  1746560        // u32[40*2] (T,kk), pad 640
#define WS_CNT     1747200        // u32[64]
#define WS_DEFK    1747456        // u64[8*3584]    =   229,376
#define WS_TIEK    1976832        // u64[40*2048]   =   655,360
#define WS_SBOX    2632192        // float4[8*3500] =   448,000
#define WS_SSC     3080192        // float[8*3500]  =   112,000
#define WS_MASK    3192192        // u64[8*98560]   = 6,307,840
#define MASK_STRIDE 98560         // words per image (packed triangle, padded)

typedef unsigned long long u64;
typedef uint32_t u32;

// Packed upper-triangle row offset: row c stores words (c>>6)..54
__device__ __forceinline__ int mask_off(int c) {
    int g = c >> 6;
    return 64 * (55 * g - (g * (g - 1)) / 2) + (c - (g << 6)) * (55 - g);
}

__device__ __forceinline__ int level_of(int p) {
    return (p < 25600) ? 0 : (p < 32000) ? 1 : (p < 33600) ? 2 : (p < 34000) ? 3 : 4;
}
__device__ __forceinline__ int loff_of(int l) {
    return (l == 0) ? 0 : (l == 1) ? 25600 : (l == 2) ? 32000 : (l == 3) ? 33600 : 34000;
}
__device__ __forceinline__ int k_of(int l) {
    return (l == 0) ? 1000 : (l == 1) ? 1000 : (l == 2) ? 1000 : (l == 3) ? 400 : 100;
}
__device__ __forceinline__ u64 readlane64(u64 v, int t) {
    u32 lo = (u32)__builtin_amdgcn_readlane((int)(u32)v, t);
    u32 hi = (u32)__builtin_amdgcn_readlane((int)(u32)(v >> 32), t);
    return ((u64)hi << 32) | lo;
}
__device__ __forceinline__ float readlanef(float v, int t) {
    return __int_as_float(__builtin_amdgcn_readlane(__float_as_int(v), t));
}

// ---------------------------------------------------------------------------
// Kernel 0: zero histograms + counters
// ---------------------------------------------------------------------------
__global__ __launch_bounds__(256)
void zero_kernel(u32* __restrict__ g) {
    const int n = (WS_CNT + 256 - WS_GHIST) / 4;
    for (int i = blockIdx.x * 256 + threadIdx.x; i < n; i += gridDim.x * 256)
        g[i] = 0u;
}

// ---------------------------------------------------------------------------
// Kernel 1: point->gt matching + sigmoid key + histogram (R7-verified, 4 pts/t)
// ---------------------------------------------------------------------------
#define MPT 4
__global__ __launch_bounds__(256)
void match_key_kernel(const float* __restrict__ points,
                      const float* __restrict__ gt,
                      const float* __restrict__ logits,
                      float* __restrict__ out_match,
                      u32* __restrict__ keys,
                      u32* __restrict__ ghist) {
#pragma clang fp contract(off)
    __shared__ float bx1[N_GT], by1[N_GT], bx2[N_GT], by2[N_GT], ar[N_GT];
    const int b = blockIdx.y;
    const int base = blockIdx.x * (256 * MPT) + threadIdx.x;

    for (int j = threadIdx.x; j < N_GT; j += 256) {
        float x1 = gt[(b * N_GT + j) * 4 + 0];
        float y1 = gt[(b * N_GT + j) * 4 + 1];
        float x2 = gt[(b * N_GT + j) * 4 + 2];
        float y2 = gt[(b * N_GT + j) * 4 + 3];
        bx1[j] = x1; by1[j] = y1; bx2[j] = x2; by2[j] = y2;
        ar[j] = (x2 - x1) * (y2 - y1);
    }
    __syncthreads();

    const float BIGF = 2147483648.0f;   // float32(2^31-1) rounds to 2^31
    float px[MPT], py[MPT], best[MPT];
    int bi[MPT];
#pragma unroll
    for (int k = 0; k < MPT; ++k) {
        int p = base + k * 256;
        int pc = (p < N_POINTS) ? p : 0;
        px[k] = points[pc * 2 + 0];
        py[k] = points[pc * 2 + 1];
        best[k] = BIGF; bi[k] = -1;
    }
    for (int j = 0; j < N_GT; ++j) {
        float x1 = bx1[j], y1 = by1[j], x2 = bx2[j], y2 = by2[j], a = ar[j];
#pragma unroll
        for (int k = 0; k < MPT; ++k) {
            bool inside = (px[k] >= x1) && (px[k] <= x2) &&
                          (py[k] >= y1) && (py[k] <= y2);
            float cost = inside ? a : BIGF;
            if (cost < best[k]) { best[k] = cost; bi[k] = j; }   // strict <
        }
    }
#pragma unroll
    for (int k = 0; k < MPT; ++k) {
        int p = base + k * 256;
        if (p >= N_POINTS) continue;
        out_match[b * N_POINTS + p] = (float)bi[k];
        float lg = logits[b * N_POINTS + p];
        float s = 1.0f / (1.0f + expf(-lg));
        u32 u = __float_as_uint(s);
        u32 key = (u & 0x80000000u) ? ~u : (u | 0x80000000u);
        keys[b * N_POINTS + p] = key;
        int seg = b * NLEV + level_of(p);
        atomicAdd(&ghist[seg * NBIN + ((key >> 19) & 4095u)], 1u);
    }
}

// ---------------------------------------------------------------------------
// Kernel 2: per-segment threshold select from histogram (one wave/segment).
// ---------------------------------------------------------------------------
__global__ __launch_bounds__(64)
void select_kernel(const u32* __restrict__ ghist, u32* __restrict__ params) {
    const int seg = blockIdx.x;
    const int l = seg % NLEV;
    const u32 K = (u32)k_of(l);
    const u32* h = ghist + seg * NBIN;
    const int lane = threadIdx.x;

    u32 S = 0;
#pragma unroll 8
    for (int i = 0; i < 64; ++i) S += h[lane * 64 + i];
    u32 acc = S;
#pragma unroll
    for (int off = 1; off < 64; off <<= 1) {
        u32 v = (u32)__shfl_down((int)acc, off);
        if (lane + off < 64) acc += v;
    }
    u32 sfxAfter = acc - S;
    bool hit = (sfxAfter < K) && (sfxAfter + S >= K);
    u64 bal = __ballot(hit);
    int Lg = (int)__builtin_ctzll(bal);
    u32 sfxG = (u32)__shfl((int)sfxAfter, Lg);

    u32 v = h[Lg * 64 + lane];
    u32 acc2 = v;
#pragma unroll
    for (int off = 1; off < 64; off <<= 1) {
        u32 t = (u32)__shfl_down((int)acc2, off);
        if (lane + off < 64) acc2 += t;
    }
    u32 sfx2 = sfxG + acc2 - v;
    bool hit2 = (sfx2 < K) && (sfx2 + v >= K);
    if (hit2) {
        params[seg * 2 + 0] = (u32)(Lg * 64 + lane);  // T
        params[seg * 2 + 1] = K - sfx2;               // kk within bin T
    }
}

// ---------------------------------------------------------------------------
// Kernel 3: one-pass compact with wave-aggregated atomics (R4 win).
// ---------------------------------------------------------------------------
__global__ __launch_bounds__(256)
void compact_kernel(const u32* __restrict__ keys,
                    const u32* __restrict__ params,
                    u32* __restrict__ cnt,
                    u64* __restrict__ defK,
                    u64* __restrict__ tieK) {
    const int idx = blockIdx.x * 256 + threadIdx.x;
    const bool active = idx < BATCH * N_POINTS;
    int b = 0, seg = 0;
    bool isDef = false, isTie = false;
    u64 k50 = 0;
    if (active) {
        b = idx / N_POINTS;
        int p = idx - b * N_POINTS;
        u32 key = keys[idx];
        int l = level_of(p);
        seg = b * NLEV + l;
        u32 T = params[seg * 2 + 0];
        u32 digit = (key >> 19) & 4095u;
        int idxl = p - loff_of(l);
        k50 = ((u64)key << 18) | ((u64)(7 - l) << 15) | (u64)(32767 - idxl);
        isDef = digit > T;
        isTie = digit == T;
    }
    const int lane = threadIdx.x & 63;
    const u64 below = (lane == 0) ? 0ull : (~0ull >> (64 - lane));

    u64 defMask = __ballot(isDef);
    while (defMask) {
        int leader = (int)__builtin_ctzll(defMask);
        int bb = __shfl(b, leader);
        u64 grp = __ballot(isDef && (b == bb));
        u32 base = 0;
        if (lane == leader)
            base = atomicAdd(&cnt[bb], (u32)__builtin_popcountll(grp));
        base = (u32)__shfl((int)base, leader);
        if (isDef && (b == bb)) {
            u32 pos = base + (u32)__builtin_popcountll(grp & below);
            defK[bb * 3584 + pos] = k50;
        }
        defMask &= ~grp;
    }
    u64 tieMask = __ballot(isTie);
    while (tieMask) {
        int leader = (int)__builtin_ctzll(tieMask);
        int sg = __shfl(seg, leader);
        u64 grp = __ballot(isTie && (seg == sg));
        u32 base = 0;
        if (lane == leader)
            base = atomicAdd(&cnt[8 + sg], (u32)__builtin_popcountll(grp));
        base = (u32)__shfl((int)base, leader);
        if (isTie && (seg == sg)) {
            u32 pos = base + (u32)__builtin_popcountll(grp & below);
            if (pos < TIE_CAP) tieK[sg * TIE_CAP + pos] = k50;
        }
        tieMask &= ~grp;
    }
}

// ---------------------------------------------------------------------------
// Kernel 4: per-image: resolve ties, then COUNTING SORT (R8: replaces the
// 78-barrier bitonic) on 12-bit digit (k50 bits 48..37, below constant MSB):
// histogram -> block suffix-scan -> scatter -> exact intra-digit rank (keys
// unique -> order bit-identical to full sort). Then decode boxes.
// ---------------------------------------------------------------------------
#define SORT_T 1024
__global__ __launch_bounds__(SORT_T)
void sortimg_kernel(const u32* __restrict__ params,
                    const u32* __restrict__ cnt,
                    const u64* __restrict__ defK,
                    const u64* __restrict__ tieK,
                    const float* __restrict__ reg,
                    const float* __restrict__ points,
                    float* __restrict__ sboxes,
                    float* __restrict__ sscores) {
#pragma clang fp contract(off)
    __shared__ u64 sk[4096];
    __shared__ u64 aux[4096];
    __shared__ u64 tb[TIE_CAP];
    __shared__ u32 h[4096];
    __shared__ u32 bs[4096];
    __shared__ u32 wt[16];
    __shared__ int s_base;
    const int b = blockIdx.x;
    const int tid = threadIdx.x;

    int nd = (int)cnt[b];
    for (int i = tid; i < nd; i += SORT_T) sk[i] = defK[b * 3584 + i];
    if (tid == 0) s_base = nd;
    __syncthreads();

    for (int s = 0; s < NLEV; ++s) {
        int seg = b * NLEV + s;
        int t = (int)cnt[8 + seg];
        if (t > TIE_CAP) t = TIE_CAP;
        int kk = (int)params[seg * 2 + 1];
        for (int i = tid; i < t; i += SORT_T) tb[i] = tieK[seg * TIE_CAP + i];
        __syncthreads();
        int base = s_base;
        for (int j = tid; j < t; j += SORT_T) {
            u64 kj = tb[j];
            int r = 0;
            for (int i = 0; i < t; ++i) r += (tb[i] > kj) ? 1 : 0;
            if (r < kk) sk[base + r] = kj;       // unique ranks -> exact fill
        }
        __syncthreads();
        if (tid == 0) s_base = base + kk;
        __syncthreads();
    }
    const int total = s_base;                    // == 3500 by construction

    // ---- counting sort by digit (descending), exact within-digit rank ----
    for (int i = tid; i < 4096; i += SORT_T) h[i] = 0u;
    __syncthreads();
    for (int i = tid; i < total; i += SORT_T)
        atomicAdd(&h[(u32)(sk[i] >> 37) & 4095u], 1u);
    __syncthreads();

    // per-thread partial over 4 reversed digits (i ascending == digit desc)
    u32 t0 = h[4095 - 4 * tid];
    u32 t1 = h[4095 - (4 * tid + 1)];
    u32 t2 = h[4095 - (4 * tid + 2)];
    u32 t3 = h[4095 - (4 * tid + 3)];
    u32 tsum = t0 + t1 + t2 + t3;
    u32 sc_ = tsum;
    const int lane = tid & 63;
#pragma unroll
    for (int off = 1; off < 64; off <<= 1) {
        u32 v = (u32)__shfl_up((int)sc_, off);
        if (lane >= off) sc_ += v;
    }
    if (lane == 63) wt[tid >> 6] = sc_;
    __syncthreads();
    if (tid < 64) {
        u32 v = (tid < 16) ? wt[tid] : 0u;
        u32 s2 = v;
#pragma unroll
        for (int off = 1; off < 16; off <<= 1) {
            u32 x = (u32)__shfl_up((int)s2, off);
            if (tid >= off) s2 += x;
        }
        if (tid < 16) wt[tid] = s2 - v;          // exclusive wave offsets
    }
    __syncthreads();
    u32 run = (sc_ - tsum) + wt[tid >> 6];       // exclusive prefix for thread
    bs[4095 - 4 * tid] = run;       run += t0;
    bs[4095 - (4 * tid + 1)] = run; run += t1;
    bs[4095 - (4 * tid + 2)] = run; run += t2;
    bs[4095 - (4 * tid + 3)] = run;
    __syncthreads();
    for (int i = tid; i < 4096; i += SORT_T) h[i] = 0u;   // fill counters
    __syncthreads();
    for (int i = tid; i < total; i += SORT_T) {
        u64 k = sk[i];
        u32 d = (u32)(k >> 37) & 4095u;
        u32 pos = bs[d] + atomicAdd(&h[d], 1u);
        aux[pos] = k;
    }
    __syncthreads();
    for (int p = tid; p < total; p += SORT_T) {
        u64 kp = aux[p];
        u32 d = (u32)(kp >> 37) & 4095u;
        u32 gbase = bs[d];
        u32 gend = (d == 0) ? (u32)total : bs[d - 1];
        u32 r = 0;
        for (u32 q = gbase; q < gend; ++q) r += (aux[q] > kp) ? 1u : 0u;
        sk[gbase + r] = kp;                      // unique keys -> exact slot
    }
    __syncthreads();

    // decode + write sorted candidates
    for (int r = tid; r < NCAND; r += SORT_T) {
        float x1 = 0.f, y1 = 0.f, x2 = 0.f, y2 = 0.f, sc = 0.f;
        if (r < total) {
            u64 k50 = sk[r];
            int lowb = (int)(k50 & 0x3FFFFull);
            int l = 7 - (lowb >> 15);
            int idxl = 32767 - (lowb & 32767);
            int p = loff_of(l) + idxl;
            u32 key32 = (u32)(k50 >> 18);
            sc = __uint_as_float(key32 ^ 0x80000000u);
            int gp = b * N_POINTS + p;
            float l_ = reg[gp * 4 + 0] * IMG;
            float t_ = reg[gp * 4 + 1] * IMG;
            float r_ = reg[gp * 4 + 2] * IMG;
            float bb = reg[gp * 4 + 3] * IMG;
            float px = points[p * 2 + 0];
            float py = points[p * 2 + 1];
            x1 = fminf(fmaxf(px - l_, 0.0f), IMG);
            y1 = fminf(fmaxf(py - t_, 0.0f), IMG);
            x2 = fminf(fmaxf(px + r_, 0.0f), IMG);
            y2 = fminf(fmaxf(py + bb, 0.0f), IMG);
        }
        int slot = b * NCAND + r;
        sboxes[slot * 4 + 0] = x1;
        sboxes[slot * 4 + 1] = y1;
        sboxes[slot * 4 + 2] = x2;
        sboxes[slot * 4 + 3] = y2;
        sscores[slot] = sc;
    }
}

// ---------------------------------------------------------------------------
// Kernel 5: suppression-mask matrix. R8: row-major again (R7 word-major
// scattered 8B stores -> 4x write-allocate inflation, WRITE_SIZE 23.8 MB).
// One wave owns 4 adjacent candidate rows: one coalesced bj load serves 4
// ballots; per-row stores walk consecutive addresses (write-combined).
// LDS-free -> high occupancy.
// ---------------------------------------------------------------------------
__global__ __launch_bounds__(256)
void mask_kernel(const float* __restrict__ sboxes,
                 const float* __restrict__ sscores,
                 u64* __restrict__ mask) {
#pragma clang fp contract(off)
    const int b = blockIdx.y;
    const int wv = threadIdx.x >> 6;
    const int lane = threadIdx.x & 63;
    const int NG = (NCAND + 3) >> 2;             // 875 row-groups
    const int gidx = blockIdx.x * 4 + wv;
    if (gidx >= NG) return;
    const int c0 = gidx << 2;

    const float4* gb = (const float4*)sboxes + b * NCAND;
    const float* gs = sscores + b * NCAND;
    u64* mout = mask + (size_t)b * MASK_STRIDE;

    float4 bc[4]; float a1[4]; bool ok[4]; int g[4]; u64* rp[4];
    bool any = false;
#pragma unroll
    for (int i = 0; i < 4; ++i) {
        int c = c0 + i;
        int cc = (c < NCAND) ? c : (NCAND - 1);
        bc[i] = gb[cc];
        a1[i] = (bc[i].z - bc[i].x) * (bc[i].w - bc[i].y);
        ok[i] = (c < NCAND) && (gs[cc] > SCORE_TH);
        g[i] = cc >> 6;
        rp[i] = mout + mask_off(cc) - g[i];
        any |= ok[i];
    }
    if (!any) return;                            // wave-uniform

    for (int w = (c0 >> 6); w < 55; ++w) {
        int cj = (w << 6) + lane;
        float4 bj = (cj < NCAND) ? gb[cj] : make_float4(0.f, 0.f, 0.f, 0.f);
        float a2 = (bj.z - bj.x) * (bj.w - bj.y);
#pragma unroll
        for (int i = 0; i < 4; ++i) {
            float x1 = fmaxf(bc[i].x, bj.x);
            float y1 = fmaxf(bc[i].y, bj.y);
            float x2 = fminf(bc[i].z, bj.z);
            float y2 = fminf(bc[i].w, bj.w);
            float inter = fmaxf(x2 - x1, 0.f) * fmaxf(y2 - y1, 0.f);
            float denom = a1[i] + a2 - inter + 1e-9f;   // ref association
            u64 bits = __ballot((double)inter > MTH * (double)denom);
            if (lane == 0 && ok[i] && w >= g[i]) rp[i][w] = bits;
        }
    }
}

// ---------------------------------------------------------------------------
// Kernel 6: sorted-order NMS scan (R7 structure: scalar readlane chain).
// ---------------------------------------------------------------------------
__global__ __launch_bounds__(64)
void scan_kernel(const float* __restrict__ sboxes,
                 const float* __restrict__ sscores,
                 const u64* __restrict__ mask,
                 float* __restrict__ out) {
    const int b = blockIdx.x;
    const int lane = threadIdx.x;            // 64 threads = 1 wave
    const float4* gb = (const float4*)sboxes + b * NCAND;
    const float* gs = sscores + b * NCAND;
    const u64* mrow = mask + (size_t)b * MASK_STRIDE;

    float* ob = out + OUT_BOXES  + b * MAX_DET * 4;
    float* os = out + OUT_SCORES + b * MAX_DET;
    float* ol = out + OUT_LABELS + b * MAX_DET;
    float* ov = out + OUT_VALID  + b * MAX_DET;

    u64 m = 0ull;                            // lane f owns future-word f
    int c0 = lane;
    u64 rowN = mrow[mask_off(c0)];
    float4 bjN = gb[c0];
    float sjN = gs[c0];

    int kept = 0;
    for (int w = 0; w < 55; ++w) {
        const int wbase = w << 6;
        const u64 row = rowN;
        const float4 bj = bjN;
        const float sj = sjN;
        if (w < 54) {
            int cn = wbase + 64 + lane;
            int cc = (cn < NCAND) ? cn : (NCAND - 1);
            rowN = mrow[mask_off(cc)];
            bjN = gb[cc];
            float s = gs[cc];
            sjN = (cn < NCAND) ? s : 0.f;
        }
        int c = wbase + lane;
        u64 bad = __ballot(!((c < NCAND) && (sj > SCORE_TH)));
        u64 cur = readlane64(m, w) | bad;
        u64 km = 0ull;
        while (kept < MAX_DET) {
            u64 avail = ~cur;
            if (avail == 0ull) break;
            int t = (int)__builtin_ctzll(avail);
            u64 r = readlane64(row, t);
            cur |= r | (1ull << t);
            km |= 1ull << t;
            float bx = readlanef(bj.x, t);
            float by = readlanef(bj.y, t);
            float bz = readlanef(bj.z, t);
            float bw = readlanef(bj.w, t);
            float sc = readlanef(sj, t);
            if (lane == 0) {
                ob[kept * 4 + 0] = bx;
                ob[kept * 4 + 1] = by;
                ob[kept * 4 + 2] = bz;
                ob[kept * 4 + 3] = bw;
                os[kept] = sc;
                ol[kept] = 0.0f;
                ov[kept] = 1.0f;
            }
            kept++;
        }
        if (km) {
            const bool lr = (lane >= w && lane < 55);
            const int lo = lane - w;
            u64 acc = 0ull;
            while (km) {
#define POPBIT(tn) int tn = -1; if (km) { tn = (int)__builtin_ctzll(km); km &= km - 1ull; }
                POPBIT(t0) POPBIT(t1) POPBIT(t2) POPBIT(t3)
                POPBIT(t4) POPBIT(t5) POPBIT(t6) POPBIT(t7)
#undef POPBIT
                u64 v0 = 0, v1 = 0, v2 = 0, v3 = 0, v4 = 0, v5 = 0, v6 = 0, v7 = 0;
                if (lr) {
                    v0 = mrow[mask_off(wbase + t0) + lo];
                    if (t1 >= 0) v1 = mrow[mask_off(wbase + t1) + lo];
                    if (t2 >= 0) v2 = mrow[mask_off(wbase + t2) + lo];
                    if (t3 >= 0) v3 = mrow[mask_off(wbase + t3) + lo];
                    if (t4 >= 0) v4 = mrow[mask_off(wbase + t4) + lo];
                    if (t5 >= 0) v5 = mrow[mask_off(wbase + t5) + lo];
                    if (t6 >= 0) v6 = mrow[mask_off(wbase + t6) + lo];
                    if (t7 >= 0) v7 = mrow[mask_off(wbase + t7) + lo];
                }
                acc |= ((v0 | v1) | (v2 | v3)) | ((v4 | v5) | (v6 | v7));
            }
            m |= acc;
        }
        if (kept >= MAX_DET) break;
    }
    for (int k = kept + lane; k < MAX_DET; k += 64) {
        ob[k * 4 + 0] = 0.f; ob[k * 4 + 1] = 0.f;
        ob[k * 4 + 2] = 0.f; ob[k * 4 + 3] = 0.f;
        os[k] = 0.f; ol[k] = -1.f; ov[k] = 0.f;
    }
}

// ---------------------------------------------------------------------------
extern "C" void kernel_launch(void* const* d_in, const int* in_sizes, int n_in,
                              void* d_out, int out_size, void* d_ws, size_t ws_size,
                              hipStream_t stream) {
    const float* points = (const float*)d_in[0];
    const float* gt     = (const float*)d_in[1];
    const float* logits = (const float*)d_in[2];
    const float* reg    = (const float*)d_in[3];
    float* out = (float*)d_out;

    u32* keys   = (u32*)((char*)d_ws + WS_KEYS);
    u32* ghist  = (u32*)((char*)d_ws + WS_GHIST);
    u32* params = (u32*)((char*)d_ws + WS_PARAMS);
    u32* cnt    = (u32*)((char*)d_ws + WS_CNT);
    u64* defK   = (u64*)((char*)d_ws + WS_DEFK);
    u64* tieK   = (u64*)((char*)d_ws + WS_TIEK);
    float* sboxes  = (float*)((char*)d_ws + WS_SBOX);
    float* sscores = (float*)((char*)d_ws + WS_SSC);
    u64* mask   = (u64*)((char*)d_ws + WS_MASK);

    zero_kernel<<<256, 256, 0, stream>>>(ghist);

    dim3 g1((N_POINTS + 256 * MPT - 1) / (256 * MPT), BATCH);
    match_key_kernel<<<g1, 256, 0, stream>>>(points, gt, logits,
                                             out + OUT_MATCH, keys, ghist);

    select_kernel<<<BATCH * NLEV, 64, 0, stream>>>(ghist, params);

    compact_kernel<<<(BATCH * N_POINTS + 255) / 256, 256, 0, stream>>>(
        keys, params, cnt, defK, tieK);

    sortimg_kernel<<<BATCH, SORT_T, 0, stream>>>(params, cnt, defK, tieK,
                                                 reg, points, sboxes, sscores);

    dim3 g5(((NCAND + 3) / 4 + 3) / 4, BATCH);   // 219 x 8 blocks, 4 rows/wave
    mask_kernel<<<g5, 256, 0, stream>>>(sboxes, sscores, mask);

    scan_kernel<<<BATCH, 64, 0, stream>>>(sboxes, sscores, mask, out);
}

// Round 9
// 325.471 us; speedup vs baseline: 1.9198x; 1.0996x over previous
//
#include <hip/hip_runtime.h>
#include <stdint.h>

// Problem constants
#define N_POINTS   34100
#define BATCH      8
#define N_GT       200
#define NLEV       5
#define NCAND      3500
#define MAX_DET    300
#define SCORE_TH   0.05f
#define NMS_TH     0.5f
#define IMG        1280.0f
#define TIE_CAP    2048
#define NBIN       4096
// Exact threshold: RN(inter/denom) > 0.5  <=>  inter_f64 > (0.5+2^-25)*denom_f64
// (verified absmax 0 since R7)
#define MTH 0.50000002980232238769531250

// Output layout (float32 flat, reference return order)
#define OUT_MATCH  0        // 8*34100
#define OUT_BOXES  272800   // 8*300*4
#define OUT_SCORES 282400   // 8*300
#define OUT_LABELS 284800   // 8*300
#define OUT_VALID  287200   // 8*300

// Workspace layout (bytes) — ghist slot retired (hist lives in LDS now)
#define WS_KEYS    0              // u32[8*34100]   = 1,091,200
#define WS_PARAMS  1746560        // u32[40*2] (T,kk)
#define WS_CNT     1747200        // u32[64]
#define WS_DEFK    1747456        // u64[8*3584]    =   229,376
#define WS_TIEK    1976832        // u64[40*2048]   =   655,360
#define WS_SBOX    2632192        // float4[8*3500] =   448,000
#define WS_SSC     3080192        // float[8*3500]  =   112,000
#define WS_MASK    3192192        // u64[8*98560]   = 6,307,840
#define MASK_STRIDE 98560         // words per image (packed triangle, padded)

typedef unsigned long long u64;
typedef uint32_t u32;

// Packed upper-triangle row offset: row c stores words (c>>6)..54
__device__ __forceinline__ int mask_off(int c) {
    int g = c >> 6;
    return 64 * (55 * g - (g * (g - 1)) / 2) + (c - (g << 6)) * (55 - g);
}

__device__ __forceinline__ int level_of(int p) {
    return (p < 25600) ? 0 : (p < 32000) ? 1 : (p < 33600) ? 2 : (p < 34000) ? 3 : 4;
}
__device__ __forceinline__ int loff_of(int l) {
    return (l == 0) ? 0 : (l == 1) ? 25600 : (l == 2) ? 32000 : (l == 3) ? 33600 : 34000;
}
__device__ __forceinline__ int lsize_of(int l) {
    return (l == 0) ? 25600 : (l == 1) ? 6400 : (l == 2) ? 1600 : (l == 3) ? 400 : 100;
}
__device__ __forceinline__ int k_of(int l) {
    return (l == 0) ? 1000 : (l == 1) ? 1000 : (l == 2) ? 1000 : (l == 3) ? 400 : 100;
}
__device__ __forceinline__ u64 readlane64(u64 v, int t) {
    u32 lo = (u32)__builtin_amdgcn_readlane((int)(u32)v, t);
    u32 hi = (u32)__builtin_amdgcn_readlane((int)(u32)(v >> 32), t);
    return ((u64)hi << 32) | lo;
}
__device__ __forceinline__ float readlanef(float v, int t) {
    return __int_as_float(__builtin_amdgcn_readlane(__float_as_int(v), t));
}

// ---------------------------------------------------------------------------
// Kernel 1: point->gt matching + sigmoid sortable key. R9: histogram atomics
// removed (were ~30 us of L2 atomic drain); MPT 4->2 for 2 blocks/CU (TLP to
// hide the per-j LDS broadcast-read chains; R8 ran 1 wave/SIMD).
// ---------------------------------------------------------------------------
#define MPT 2
__global__ __launch_bounds__(256)
void match_key_kernel(const float* __restrict__ points,
                      const float* __restrict__ gt,
                      const float* __restrict__ logits,
                      float* __restrict__ out_match,
                      u32* __restrict__ keys) {
#pragma clang fp contract(off)
    __shared__ float bx1[N_GT], by1[N_GT], bx2[N_GT], by2[N_GT], ar[N_GT];
    const int b = blockIdx.y;
    const int base = blockIdx.x * (256 * MPT) + threadIdx.x;

    for (int j = threadIdx.x; j < N_GT; j += 256) {
        float x1 = gt[(b * N_GT + j) * 4 + 0];
        float y1 = gt[(b * N_GT + j) * 4 + 1];
        float x2 = gt[(b * N_GT + j) * 4 + 2];
        float y2 = gt[(b * N_GT + j) * 4 + 3];
        bx1[j] = x1; by1[j] = y1; bx2[j] = x2; by2[j] = y2;
        ar[j] = (x2 - x1) * (y2 - y1);
    }
    __syncthreads();

    const float BIGF = 2147483648.0f;   // float32(2^31-1) rounds to 2^31
    float px[MPT], py[MPT], best[MPT];
    int bi[MPT];
#pragma unroll
    for (int k = 0; k < MPT; ++k) {
        int p = base + k * 256;
        int pc = (p < N_POINTS) ? p : 0;
        px[k] = points[pc * 2 + 0];
        py[k] = points[pc * 2 + 1];
        best[k] = BIGF; bi[k] = -1;
    }
    for (int j = 0; j < N_GT; ++j) {
        float x1 = bx1[j], y1 = by1[j], x2 = bx2[j], y2 = by2[j], a = ar[j];
#pragma unroll
        for (int k = 0; k < MPT; ++k) {
            bool inside = (px[k] >= x1) && (px[k] <= x2) &&
                          (py[k] >= y1) && (py[k] <= y2);
            float cost = inside ? a : BIGF;
            if (cost < best[k]) { best[k] = cost; bi[k] = j; }   // strict <
        }
    }
#pragma unroll
    for (int k = 0; k < MPT; ++k) {
        int p = base + k * 256;
        if (p >= N_POINTS) continue;
        out_match[b * N_POINTS + p] = (float)bi[k];
        float lg = logits[b * N_POINTS + p];
        float s = 1.0f / (1.0f + expf(-lg));
        u32 u = __float_as_uint(s);
        u32 key = (u & 0x80000000u) ? ~u : (u | 0x80000000u);
        keys[b * N_POINTS + p] = key;
    }
}

// ---------------------------------------------------------------------------
// Kernel 2: R9 fused histogram + threshold select. One block per segment:
// LDS 4096-bin histogram (LDS atomics ~4 cyc vs L2 ~40), then wave-0 suffix
// scan finds T (threshold digit) and kk (count within T). Also zeroes cnt.
// Replaces zero/ghist/select — 2 launches and all global hist traffic gone.
// ---------------------------------------------------------------------------
__global__ __launch_bounds__(256)
void hist_select_kernel(const u32* __restrict__ keys,
                        u32* __restrict__ params,
                        u32* __restrict__ cnt) {
    __shared__ u32 h[NBIN];
    const int seg = blockIdx.x;              // b*5 + l
    const int b = seg / NLEV;
    const int l = seg - b * NLEV;
    const int tid = threadIdx.x;

    for (int i = tid; i < NBIN; i += 256) h[i] = 0u;
    if (seg == 0 && tid < 64) cnt[tid] = 0u;
    __syncthreads();

    const u32* k = keys + b * N_POINTS + loff_of(l);
    const int n = lsize_of(l);
    for (int i = tid; i < n; i += 256)
        atomicAdd(&h[(k[i] >> 19) & 4095u], 1u);
    __syncthreads();

    if (tid < 64) {
        const u32 K = (u32)k_of(l);
        const int lane = tid;
        u32 S = 0;
#pragma unroll 8
        for (int i = 0; i < 64; ++i) S += h[lane * 64 + i];
        u32 acc = S;
#pragma unroll
        for (int off = 1; off < 64; off <<= 1) {
            u32 v = (u32)__shfl_down((int)acc, off);
            if (lane + off < 64) acc += v;
        }
        u32 sfxAfter = acc - S;
        bool hit = (sfxAfter < K) && (sfxAfter + S >= K);
        u64 bal = __ballot(hit);
        int Lg = (int)__builtin_ctzll(bal);
        u32 sfxG = (u32)__shfl((int)sfxAfter, Lg);

        u32 v = h[Lg * 64 + lane];
        u32 acc2 = v;
#pragma unroll
        for (int off = 1; off < 64; off <<= 1) {
            u32 t = (u32)__shfl_down((int)acc2, off);
            if (lane + off < 64) acc2 += t;
        }
        u32 sfx2 = sfxG + acc2 - v;
        bool hit2 = (sfx2 < K) && (sfx2 + v >= K);
        if (hit2) {
            params[seg * 2 + 0] = (u32)(Lg * 64 + lane);  // T
            params[seg * 2 + 1] = K - sfx2;               // kk within bin T
        }
    }
}

// ---------------------------------------------------------------------------
// Kernel 3: one-pass compact with wave-aggregated atomics (R4 win).
// ---------------------------------------------------------------------------
__global__ __launch_bounds__(256)
void compact_kernel(const u32* __restrict__ keys,
                    const u32* __restrict__ params,
                    u32* __restrict__ cnt,
                    u64* __restrict__ defK,
                    u64* __restrict__ tieK) {
    const int idx = blockIdx.x * 256 + threadIdx.x;
    const bool active = idx < BATCH * N_POINTS;
    int b = 0, seg = 0;
    bool isDef = false, isTie = false;
    u64 k50 = 0;
    if (active) {
        b = idx / N_POINTS;
        int p = idx - b * N_POINTS;
        u32 key = keys[idx];
        int l = level_of(p);
        seg = b * NLEV + l;
        u32 T = params[seg * 2 + 0];
        u32 digit = (key >> 19) & 4095u;
        int idxl = p - loff_of(l);
        k50 = ((u64)key << 18) | ((u64)(7 - l) << 15) | (u64)(32767 - idxl);
        isDef = digit > T;
        isTie = digit == T;
    }
    const int lane = threadIdx.x & 63;
    const u64 below = (lane == 0) ? 0ull : (~0ull >> (64 - lane));

    u64 defMask = __ballot(isDef);
    while (defMask) {
        int leader = (int)__builtin_ctzll(defMask);
        int bb = __shfl(b, leader);
        u64 grp = __ballot(isDef && (b == bb));
        u32 base = 0;
        if (lane == leader)
            base = atomicAdd(&cnt[bb], (u32)__builtin_popcountll(grp));
        base = (u32)__shfl((int)base, leader);
        if (isDef && (b == bb)) {
            u32 pos = base + (u32)__builtin_popcountll(grp & below);
            defK[bb * 3584 + pos] = k50;
        }
        defMask &= ~grp;
    }
    u64 tieMask = __ballot(isTie);
    while (tieMask) {
        int leader = (int)__builtin_ctzll(tieMask);
        int sg = __shfl(seg, leader);
        u64 grp = __ballot(isTie && (seg == sg));
        u32 base = 0;
        if (lane == leader)
            base = atomicAdd(&cnt[8 + sg], (u32)__builtin_popcountll(grp));
        base = (u32)__shfl((int)base, leader);
        if (isTie && (seg == sg)) {
            u32 pos = base + (u32)__builtin_popcountll(grp & below);
            if (pos < TIE_CAP) tieK[sg * TIE_CAP + pos] = k50;
        }
        tieMask &= ~grp;
    }
}

// ---------------------------------------------------------------------------
// Kernel 4: per-image: resolve ties, counting sort (R8-verified), decode.
// ---------------------------------------------------------------------------
#define SORT_T 1024
__global__ __launch_bounds__(SORT_T)
void sortimg_kernel(const u32* __restrict__ params,
                    const u32* __restrict__ cnt,
                    const u64* __restrict__ defK,
                    const u64* __restrict__ tieK,
                    const float* __restrict__ reg,
                    const float* __restrict__ points,
                    float* __restrict__ sboxes,
                    float* __restrict__ sscores) {
#pragma clang fp contract(off)
    __shared__ u64 sk[4096];
    __shared__ u64 aux[4096];
    __shared__ u64 tb[TIE_CAP];
    __shared__ u32 h[4096];
    __shared__ u32 bs[4096];
    __shared__ u32 wt[16];
    __shared__ int s_base;
    const int b = blockIdx.x;
    const int tid = threadIdx.x;

    int nd = (int)cnt[b];
    for (int i = tid; i < nd; i += SORT_T) sk[i] = defK[b * 3584 + i];
    if (tid == 0) s_base = nd;
    __syncthreads();

    for (int s = 0; s < NLEV; ++s) {
        int seg = b * NLEV + s;
        int t = (int)cnt[8 + seg];
        if (t > TIE_CAP) t = TIE_CAP;
        int kk = (int)params[seg * 2 + 1];
        for (int i = tid; i < t; i += SORT_T) tb[i] = tieK[seg * TIE_CAP + i];
        __syncthreads();
        int base = s_base;
        for (int j = tid; j < t; j += SORT_T) {
            u64 kj = tb[j];
            int r = 0;
            for (int i = 0; i < t; ++i) r += (tb[i] > kj) ? 1 : 0;
            if (r < kk) sk[base + r] = kj;       // unique ranks -> exact fill
        }
        __syncthreads();
        if (tid == 0) s_base = base + kk;
        __syncthreads();
    }
    const int total = s_base;                    // == 3500 by construction

    // ---- counting sort by digit (descending), exact within-digit rank ----
    for (int i = tid; i < 4096; i += SORT_T) h[i] = 0u;
    __syncthreads();
    for (int i = tid; i < total; i += SORT_T)
        atomicAdd(&h[(u32)(sk[i] >> 37) & 4095u], 1u);
    __syncthreads();

    u32 t0 = h[4095 - 4 * tid];
    u32 t1 = h[4095 - (4 * tid + 1)];
    u32 t2 = h[4095 - (4 * tid + 2)];
    u32 t3 = h[4095 - (4 * tid + 3)];
    u32 tsum = t0 + t1 + t2 + t3;
    u32 sc_ = tsum;
    const int lane = tid & 63;
#pragma unroll
    for (int off = 1; off < 64; off <<= 1) {
        u32 v = (u32)__shfl_up((int)sc_, off);
        if (lane >= off) sc_ += v;
    }
    if (lane == 63) wt[tid >> 6] = sc_;
    __syncthreads();
    if (tid < 64) {
        u32 v = (tid < 16) ? wt[tid] : 0u;
        u32 s2 = v;
#pragma unroll
        for (int off = 1; off < 16; off <<= 1) {
            u32 x = (u32)__shfl_up((int)s2, off);
            if (tid >= off) s2 += x;
        }
        if (tid < 16) wt[tid] = s2 - v;          // exclusive wave offsets
    }
    __syncthreads();
    u32 run = (sc_ - tsum) + wt[tid >> 6];
    bs[4095 - 4 * tid] = run;       run += t0;
    bs[4095 - (4 * tid + 1)] = run; run += t1;
    bs[4095 - (4 * tid + 2)] = run; run += t2;
    bs[4095 - (4 * tid + 3)] = run;
    __syncthreads();
    for (int i = tid; i < 4096; i += SORT_T) h[i] = 0u;
    __syncthreads();
    for (int i = tid; i < total; i += SORT_T) {
        u64 k = sk[i];
        u32 d = (u32)(k >> 37) & 4095u;
        u32 pos = bs[d] + atomicAdd(&h[d], 1u);
        aux[pos] = k;
    }
    __syncthreads();
    for (int p = tid; p < total; p += SORT_T) {
        u64 kp = aux[p];
        u32 d = (u32)(kp >> 37) & 4095u;
        u32 gbase = bs[d];
        u32 gend = (d == 0) ? (u32)total : bs[d - 1];
        u32 r = 0;
        for (u32 q = gbase; q < gend; ++q) r += (aux[q] > kp) ? 1u : 0u;
        sk[gbase + r] = kp;                      // unique keys -> exact slot
    }
    __syncthreads();

    for (int r = tid; r < NCAND; r += SORT_T) {
        float x1 = 0.f, y1 = 0.f, x2 = 0.f, y2 = 0.f, sc = 0.f;
        if (r < total) {
            u64 k50 = sk[r];
            int lowb = (int)(k50 & 0x3FFFFull);
            int l = 7 - (lowb >> 15);
            int idxl = 32767 - (lowb & 32767);
            int p = loff_of(l) + idxl;
            u32 key32 = (u32)(k50 >> 18);
            sc = __uint_as_float(key32 ^ 0x80000000u);
            int gp = b * N_POINTS + p;
            float l_ = reg[gp * 4 + 0] * IMG;
            float t_ = reg[gp * 4 + 1] * IMG;
            float r_ = reg[gp * 4 + 2] * IMG;
            float bb = reg[gp * 4 + 3] * IMG;
            float px = points[p * 2 + 0];
            float py = points[p * 2 + 1];
            x1 = fminf(fmaxf(px - l_, 0.0f), IMG);
            y1 = fminf(fmaxf(py - t_, 0.0f), IMG);
            x2 = fminf(fmaxf(px + r_, 0.0f), IMG);
            y2 = fminf(fmaxf(py + bb, 0.0f), IMG);
        }
        int slot = b * NCAND + r;
        sboxes[slot * 4 + 0] = x1;
        sboxes[slot * 4 + 1] = y1;
        sboxes[slot * 4 + 2] = x2;
        sboxes[slot * 4 + 3] = y2;
        sscores[slot] = sc;
    }
}

// ---------------------------------------------------------------------------
// Kernel 5: suppression-mask matrix (R8-verified row-major, 4 rows/wave).
// ---------------------------------------------------------------------------
__global__ __launch_bounds__(256)
void mask_kernel(const float* __restrict__ sboxes,
                 const float* __restrict__ sscores,
                 u64* __restrict__ mask) {
#pragma clang fp contract(off)
    const int b = blockIdx.y;
    const int wv = threadIdx.x >> 6;
    const int lane = threadIdx.x & 63;
    const int NG = (NCAND + 3) >> 2;             // 875 row-groups
    const int gidx = blockIdx.x * 4 + wv;
    if (gidx >= NG) return;
    const int c0 = gidx << 2;

    const float4* gb = (const float4*)sboxes + b * NCAND;
    const float* gs = sscores + b * NCAND;
    u64* mout = mask + (size_t)b * MASK_STRIDE;

    float4 bc[4]; float a1[4]; bool ok[4]; int g[4]; u64* rp[4];
    bool any = false;
#pragma unroll
    for (int i = 0; i < 4; ++i) {
        int c = c0 + i;
        int cc = (c < NCAND) ? c : (NCAND - 1);
        bc[i] = gb[cc];
        a1[i] = (bc[i].z - bc[i].x) * (bc[i].w - bc[i].y);
        ok[i] = (c < NCAND) && (gs[cc] > SCORE_TH);
        g[i] = cc >> 6;
        rp[i] = mout + mask_off(cc) - g[i];
        any |= ok[i];
    }
    if (!any) return;                            // wave-uniform

    for (int w = (c0 >> 6); w < 55; ++w) {
        int cj = (w << 6) + lane;
        float4 bj = (cj < NCAND) ? gb[cj] : make_float4(0.f, 0.f, 0.f, 0.f);
        float a2 = (bj.z - bj.x) * (bj.w - bj.y);
#pragma unroll
        for (int i = 0; i < 4; ++i) {
            float x1 = fmaxf(bc[i].x, bj.x);
            float y1 = fmaxf(bc[i].y, bj.y);
            float x2 = fminf(bc[i].z, bj.z);
            float y2 = fminf(bc[i].w, bj.w);
            float inter = fmaxf(x2 - x1, 0.f) * fmaxf(y2 - y1, 0.f);
            float denom = a1[i] + a2 - inter + 1e-9f;   // ref association
            u64 bits = __ballot((double)inter > MTH * (double)denom);
            if (lane == 0 && ok[i] && w >= g[i]) rp[i][w] = bits;
        }
    }
}

// ---------------------------------------------------------------------------
// Kernel 6: sorted-order NMS scan (R7/R8-verified scalar readlane chain).
// ---------------------------------------------------------------------------
__global__ __launch_bounds__(64)
void scan_kernel(const float* __restrict__ sboxes,
                 const float* __restrict__ sscores,
                 const u64* __restrict__ mask,
                 float* __restrict__ out) {
    const int b = blockIdx.x;
    const int lane = threadIdx.x;            // 64 threads = 1 wave
    const float4* gb = (const float4*)sboxes + b * NCAND;
    const float* gs = sscores + b * NCAND;
    const u64* mrow = mask + (size_t)b * MASK_STRIDE;

    float* ob = out + OUT_BOXES  + b * MAX_DET * 4;
    float* os = out + OUT_SCORES + b * MAX_DET;
    float* ol = out + OUT_LABELS + b * MAX_DET;
    float* ov = out + OUT_VALID  + b * MAX_DET;

    u64 m = 0ull;                            // lane f owns future-word f
    int c0 = lane;
    u64 rowN = mrow[mask_off(c0)];
    float4 bjN = gb[c0];
    float sjN = gs[c0];

    int kept = 0;
    for (int w = 0; w < 55; ++w) {
        const int wbase = w << 6;
        const u64 row = rowN;
        const float4 bj = bjN;
        const float sj = sjN;
        if (w < 54) {
            int cn = wbase + 64 + lane;
            int cc = (cn < NCAND) ? cn : (NCAND - 1);
            rowN = mrow[mask_off(cc)];
            bjN = gb[cc];
            float s = gs[cc];
            sjN = (cn < NCAND) ? s : 0.f;
        }
        int c = wbase + lane;
        u64 bad = __ballot(!((c < NCAND) && (sj > SCORE_TH)));
        u64 cur = readlane64(m, w) | bad;
        u64 km = 0ull;
        while (kept < MAX_DET) {
            u64 avail = ~cur;
            if (avail == 0ull) break;
            int t = (int)__builtin_ctzll(avail);
            u64 r = readlane64(row, t);
            cur |= r | (1ull << t);
            km |= 1ull << t;
            float bx = readlanef(bj.x, t);
            float by = readlanef(bj.y, t);
            float bz = readlanef(bj.z, t);
            float bw = readlanef(bj.w, t);
            float sc = readlanef(sj, t);
            if (lane == 0) {
                ob[kept * 4 + 0] = bx;
                ob[kept * 4 + 1] = by;
                ob[kept * 4 + 2] = bz;
                ob[kept * 4 + 3] = bw;
                os[kept] = sc;
                ol[kept] = 0.0f;
                ov[kept] = 1.0f;
            }
            kept++;
        }
        if (km) {
            const bool lr = (lane >= w && lane < 55);
            const int lo = lane - w;
            u64 acc = 0ull;
            while (km) {
#define POPBIT(tn) int tn = -1; if (km) { tn = (int)__builtin_ctzll(km); km &= km - 1ull; }
                POPBIT(t0) POPBIT(t1) POPBIT(t2) POPBIT(t3)
                POPBIT(t4) POPBIT(t5) POPBIT(t6) POPBIT(t7)
#undef POPBIT
                u64 v0 = 0, v1 = 0, v2 = 0, v3 = 0, v4 = 0, v5 = 0, v6 = 0, v7 = 0;
                if (lr) {
                    v0 = mrow[mask_off(wbase + t0) + lo];
                    if (t1 >= 0) v1 = mrow[mask_off(wbase + t1) + lo];
                    if (t2 >= 0) v2 = mrow[mask_off(wbase + t2) + lo];
                    if (t3 >= 0) v3 = mrow[mask_off(wbase + t3) + lo];
                    if (t4 >= 0) v4 = mrow[mask_off(wbase + t4) + lo];
                    if (t5 >= 0) v5 = mrow[mask_off(wbase + t5) + lo];
                    if (t6 >= 0) v6 = mrow[mask_off(wbase + t6) + lo];
                    if (t7 >= 0) v7 = mrow[mask_off(wbase + t7) + lo];
                }
                acc |= ((v0 | v1) | (v2 | v3)) | ((v4 | v5) | (v6 | v7));
            }
            m |= acc;
        }
        if (kept >= MAX_DET) break;
    }
    for (int k = kept + lane; k < MAX_DET; k += 64) {
        ob[k * 4 + 0] = 0.f; ob[k * 4 + 1] = 0.f;
        ob[k * 4 + 2] = 0.f; ob[k * 4 + 3] = 0.f;
        os[k] = 0.f; ol[k] = -1.f; ov[k] = 0.f;
    }
}

// ---------------------------------------------------------------------------
extern "C" void kernel_launch(void* const* d_in, const int* in_sizes, int n_in,
                              void* d_out, int out_size, void* d_ws, size_t ws_size,
                              hipStream_t stream) {
    const float* points = (const float*)d_in[0];
    const float* gt     = (const float*)d_in[1];
    const float* logits = (const float*)d_in[2];
    const float* reg    = (const float*)d_in[3];
    float* out = (float*)d_out;

    u32* keys   = (u32*)((char*)d_ws + WS_KEYS);
    u32* params = (u32*)((char*)d_ws + WS_PARAMS);
    u32* cnt    = (u32*)((char*)d_ws + WS_CNT);
    u64* defK   = (u64*)((char*)d_ws + WS_DEFK);
    u64* tieK   = (u64*)((char*)d_ws + WS_TIEK);
    float* sboxes  = (float*)((char*)d_ws + WS_SBOX);
    float* sscores = (float*)((char*)d_ws + WS_SSC);
    u64* mask   = (u64*)((char*)d_ws + WS_MASK);

    dim3 g1((N_POINTS + 256 * MPT - 1) / (256 * MPT), BATCH);
    match_key_kernel<<<g1, 256, 0, stream>>>(points, gt, logits,
                                             out + OUT_MATCH, keys);

    hist_select_kernel<<<BATCH * NLEV, 256, 0, stream>>>(keys, params, cnt);

    compact_kernel<<<(BATCH * N_POINTS + 255) / 256, 256, 0, stream>>>(
        keys, params, cnt, defK, tieK);

    sortimg_kernel<<<BATCH, SORT_T, 0, stream>>>(params, cnt, defK, tieK,
                                                 reg, points, sboxes, sscores);

    dim3 g5(((NCAND + 3) / 4 + 3) / 4, BATCH);   // 219 x 8 blocks, 4 rows/wave
    mask_kernel<<<g5, 256, 0, stream>>>(sboxes, sscores, mask);

    scan_kernel<<<BATCH, 64, 0, stream>>>(sboxes, sscores, mask, out);
}

// Round 10
// 323.690 us; speedup vs baseline: 1.9304x; 1.0055x over previous
//
#include <hip/hip_runtime.h>
#include <stdint.h>

// Problem constants
#define N_POINTS   34100
#define BATCH      8
#define N_GT       200
#define NLEV       5
#define NCAND      3500
#define MAX_DET    300
#define SCORE_TH   0.05f
#define NMS_TH     0.5f
#define IMG        1280.0f
#define TIE_CAP    2048
#define NBIN       4096
// Exact threshold: RN(inter/denom) > 0.5  <=>  inter_f64 > (0.5+2^-25)*denom_f64
// (verified absmax 0 since R7)
#define MTH 0.50000002980232238769531250

// Output layout (float32 flat, reference return order)
#define OUT_MATCH  0        // 8*34100
#define OUT_BOXES  272800   // 8*300*4
#define OUT_SCORES 282400   // 8*300
#define OUT_LABELS 284800   // 8*300
#define OUT_VALID  287200   // 8*300

// Workspace layout (bytes)
#define WS_KEYS    0              // u32[8*34100]   = 1,091,200
#define WS_PARAMS  1746560        // u32[40*2] (T,kk)
#define WS_CNT     1747200        // u32[64]
#define WS_DEFK    1747456        // u64[8*3584]    =   229,376
#define WS_TIEK    1976832        // u64[40*2048]   =   655,360
#define WS_SBOX    2632192        // float4[8*3500] =   448,000
#define WS_SSC     3080192        // float[8*3500]  =   112,000
#define WS_MASK    3192192        // u64[8*98560]   = 6,307,840
#define WS_DIAG    9500032        // u64[8*3520]    =   225,280 (R10: dense diagonal blocks)
#define MASK_STRIDE 98560         // words per image (packed triangle, padded)
#define DIAG_STRIDE 3520

typedef unsigned long long u64;
typedef uint32_t u32;

// Packed upper-triangle row offset: row c stores words (c>>6)..54
__device__ __forceinline__ int mask_off(int c) {
    int g = c >> 6;
    return 64 * (55 * g - (g * (g - 1)) / 2) + (c - (g << 6)) * (55 - g);
}

__device__ __forceinline__ int level_of(int p) {
    return (p < 25600) ? 0 : (p < 32000) ? 1 : (p < 33600) ? 2 : (p < 34000) ? 3 : 4;
}
__device__ __forceinline__ int loff_of(int l) {
    return (l == 0) ? 0 : (l == 1) ? 25600 : (l == 2) ? 32000 : (l == 3) ? 33600 : 34000;
}
__device__ __forceinline__ int lsize_of(int l) {
    return (l == 0) ? 25600 : (l == 1) ? 6400 : (l == 2) ? 1600 : (l == 3) ? 400 : 100;
}
__device__ __forceinline__ int k_of(int l) {
    return (l == 0) ? 1000 : (l == 1) ? 1000 : (l == 2) ? 1000 : (l == 3) ? 400 : 100;
}
__device__ __forceinline__ u64 readlane64(u64 v, int t) {
    u32 lo = (u32)__builtin_amdgcn_readlane((int)(u32)v, t);
    u32 hi = (u32)__builtin_amdgcn_readlane((int)(u32)(v >> 32), t);
    return ((u64)hi << 32) | lo;
}

// ---------------------------------------------------------------------------
// Kernel 1: point->gt matching + sigmoid sortable key (R9-verified).
// ---------------------------------------------------------------------------
#define MPT 2
__global__ __launch_bounds__(256)
void match_key_kernel(const float* __restrict__ points,
                      const float* __restrict__ gt,
                      const float* __restrict__ logits,
                      float* __restrict__ out_match,
                      u32* __restrict__ keys) {
#pragma clang fp contract(off)
    __shared__ float bx1[N_GT], by1[N_GT], bx2[N_GT], by2[N_GT], ar[N_GT];
    const int b = blockIdx.y;
    const int base = blockIdx.x * (256 * MPT) + threadIdx.x;

    for (int j = threadIdx.x; j < N_GT; j += 256) {
        float x1 = gt[(b * N_GT + j) * 4 + 0];
        float y1 = gt[(b * N_GT + j) * 4 + 1];
        float x2 = gt[(b * N_GT + j) * 4 + 2];
        float y2 = gt[(b * N_GT + j) * 4 + 3];
        bx1[j] = x1; by1[j] = y1; bx2[j] = x2; by2[j] = y2;
        ar[j] = (x2 - x1) * (y2 - y1);
    }
    __syncthreads();

    const float BIGF = 2147483648.0f;   // float32(2^31-1) rounds to 2^31
    float px[MPT], py[MPT], best[MPT];
    int bi[MPT];
#pragma unroll
    for (int k = 0; k < MPT; ++k) {
        int p = base + k * 256;
        int pc = (p < N_POINTS) ? p : 0;
        px[k] = points[pc * 2 + 0];
        py[k] = points[pc * 2 + 1];
        best[k] = BIGF; bi[k] = -1;
    }
    for (int j = 0; j < N_GT; ++j) {
        float x1 = bx1[j], y1 = by1[j], x2 = bx2[j], y2 = by2[j], a = ar[j];
#pragma unroll
        for (int k = 0; k < MPT; ++k) {
            bool inside = (px[k] >= x1) && (px[k] <= x2) &&
                          (py[k] >= y1) && (py[k] <= y2);
            float cost = inside ? a : BIGF;
            if (cost < best[k]) { best[k] = cost; bi[k] = j; }   // strict <
        }
    }
#pragma unroll
    for (int k = 0; k < MPT; ++k) {
        int p = base + k * 256;
        if (p >= N_POINTS) continue;
        out_match[b * N_POINTS + p] = (float)bi[k];
        float lg = logits[b * N_POINTS + p];
        float s = 1.0f / (1.0f + expf(-lg));
        u32 u = __float_as_uint(s);
        u32 key = (u & 0x80000000u) ? ~u : (u | 0x80000000u);
        keys[b * N_POINTS + p] = key;
    }
}

// ---------------------------------------------------------------------------
// Kernel 2: fused LDS histogram + threshold select (R9-verified).
// ---------------------------------------------------------------------------
__global__ __launch_bounds__(256)
void hist_select_kernel(const u32* __restrict__ keys,
                        u32* __restrict__ params,
                        u32* __restrict__ cnt) {
    __shared__ u32 h[NBIN];
    const int seg = blockIdx.x;              // b*5 + l
    const int b = seg / NLEV;
    const int l = seg - b * NLEV;
    const int tid = threadIdx.x;

    for (int i = tid; i < NBIN; i += 256) h[i] = 0u;
    if (seg == 0 && tid < 64) cnt[tid] = 0u;
    __syncthreads();

    const u32* k = keys + b * N_POINTS + loff_of(l);
    const int n = lsize_of(l);
    for (int i = tid; i < n; i += 256)
        atomicAdd(&h[(k[i] >> 19) & 4095u], 1u);
    __syncthreads();

    if (tid < 64) {
        const u32 K = (u32)k_of(l);
        const int lane = tid;
        u32 S = 0;
#pragma unroll 8
        for (int i = 0; i < 64; ++i) S += h[lane * 64 + i];
        u32 acc = S;
#pragma unroll
        for (int off = 1; off < 64; off <<= 1) {
            u32 v = (u32)__shfl_down((int)acc, off);
            if (lane + off < 64) acc += v;
        }
        u32 sfxAfter = acc - S;
        bool hit = (sfxAfter < K) && (sfxAfter + S >= K);
        u64 bal = __ballot(hit);
        int Lg = (int)__builtin_ctzll(bal);
        u32 sfxG = (u32)__shfl((int)sfxAfter, Lg);

        u32 v = h[Lg * 64 + lane];
        u32 acc2 = v;
#pragma unroll
        for (int off = 1; off < 64; off <<= 1) {
            u32 t = (u32)__shfl_down((int)acc2, off);
            if (lane + off < 64) acc2 += t;
        }
        u32 sfx2 = sfxG + acc2 - v;
        bool hit2 = (sfx2 < K) && (sfx2 + v >= K);
        if (hit2) {
            params[seg * 2 + 0] = (u32)(Lg * 64 + lane);  // T
            params[seg * 2 + 1] = K - sfx2;               // kk within bin T
        }
    }
}

// ---------------------------------------------------------------------------
// Kernel 3: one-pass compact with wave-aggregated atomics (R4 win).
// ---------------------------------------------------------------------------
__global__ __launch_bounds__(256)
void compact_kernel(const u32* __restrict__ keys,
                    const u32* __restrict__ params,
                    u32* __restrict__ cnt,
                    u64* __restrict__ defK,
                    u64* __restrict__ tieK) {
    const int idx = blockIdx.x * 256 + threadIdx.x;
    const bool active = idx < BATCH * N_POINTS;
    int b = 0, seg = 0;
    bool isDef = false, isTie = false;
    u64 k50 = 0;
    if (active) {
        b = idx / N_POINTS;
        int p = idx - b * N_POINTS;
        u32 key = keys[idx];
        int l = level_of(p);
        seg = b * NLEV + l;
        u32 T = params[seg * 2 + 0];
        u32 digit = (key >> 19) & 4095u;
        int idxl = p - loff_of(l);
        k50 = ((u64)key << 18) | ((u64)(7 - l) << 15) | (u64)(32767 - idxl);
        isDef = digit > T;
        isTie = digit == T;
    }
    const int lane = threadIdx.x & 63;
    const u64 below = (lane == 0) ? 0ull : (~0ull >> (64 - lane));

    u64 defMask = __ballot(isDef);
    while (defMask) {
        int leader = (int)__builtin_ctzll(defMask);
        int bb = __shfl(b, leader);
        u64 grp = __ballot(isDef && (b == bb));
        u32 base = 0;
        if (lane == leader)
            base = atomicAdd(&cnt[bb], (u32)__builtin_popcountll(grp));
        base = (u32)__shfl((int)base, leader);
        if (isDef && (b == bb)) {
            u32 pos = base + (u32)__builtin_popcountll(grp & below);
            defK[bb * 3584 + pos] = k50;
        }
        defMask &= ~grp;
    }
    u64 tieMask = __ballot(isTie);
    while (tieMask) {
        int leader = (int)__builtin_ctzll(tieMask);
        int sg = __shfl(seg, leader);
        u64 grp = __ballot(isTie && (seg == sg));
        u32 base = 0;
        if (lane == leader)
            base = atomicAdd(&cnt[8 + sg], (u32)__builtin_popcountll(grp));
        base = (u32)__shfl((int)base, leader);
        if (isTie && (seg == sg)) {
            u32 pos = base + (u32)__builtin_popcountll(grp & below);
            if (pos < TIE_CAP) tieK[sg * TIE_CAP + pos] = k50;
        }
        tieMask &= ~grp;
    }
}

// ---------------------------------------------------------------------------
// Kernel 4: per-image: resolve ties, counting sort (R8-verified), decode.
// ---------------------------------------------------------------------------
#define SORT_T 1024
__global__ __launch_bounds__(SORT_T)
void sortimg_kernel(const u32* __restrict__ params,
                    const u32* __restrict__ cnt,
                    const u64* __restrict__ defK,
                    const u64* __restrict__ tieK,
                    const float* __restrict__ reg,
                    const float* __restrict__ points,
                    float* __restrict__ sboxes,
                    float* __restrict__ sscores) {
#pragma clang fp contract(off)
    __shared__ u64 sk[4096];
    __shared__ u64 aux[4096];
    __shared__ u64 tb[TIE_CAP];
    __shared__ u32 h[4096];
    __shared__ u32 bs[4096];
    __shared__ u32 wt[16];
    __shared__ int s_base;
    const int b = blockIdx.x;
    const int tid = threadIdx.x;

    int nd = (int)cnt[b];
    for (int i = tid; i < nd; i += SORT_T) sk[i] = defK[b * 3584 + i];
    if (tid == 0) s_base = nd;
    __syncthreads();

    for (int s = 0; s < NLEV; ++s) {
        int seg = b * NLEV + s;
        int t = (int)cnt[8 + seg];
        if (t > TIE_CAP) t = TIE_CAP;
        int kk = (int)params[seg * 2 + 1];
        for (int i = tid; i < t; i += SORT_T) tb[i] = tieK[seg * TIE_CAP + i];
        __syncthreads();
        int base = s_base;
        for (int j = tid; j < t; j += SORT_T) {
            u64 kj = tb[j];
            int r = 0;
            for (int i = 0; i < t; ++i) r += (tb[i] > kj) ? 1 : 0;
            if (r < kk) sk[base + r] = kj;       // unique ranks -> exact fill
        }
        __syncthreads();
        if (tid == 0) s_base = base + kk;
        __syncthreads();
    }
    const int total = s_base;                    // == 3500 by construction

    for (int i = tid; i < 4096; i += SORT_T) h[i] = 0u;
    __syncthreads();
    for (int i = tid; i < total; i += SORT_T)
        atomicAdd(&h[(u32)(sk[i] >> 37) & 4095u], 1u);
    __syncthreads();

    u32 t0 = h[4095 - 4 * tid];
    u32 t1 = h[4095 - (4 * tid + 1)];
    u32 t2 = h[4095 - (4 * tid + 2)];
    u32 t3 = h[4095 - (4 * tid + 3)];
    u32 tsum = t0 + t1 + t2 + t3;
    u32 sc_ = tsum;
    const int lane = tid & 63;
#pragma unroll
    for (int off = 1; off < 64; off <<= 1) {
        u32 v = (u32)__shfl_up((int)sc_, off);
        if (lane >= off) sc_ += v;
    }
    if (lane == 63) wt[tid >> 6] = sc_;
    __syncthreads();
    if (tid < 64) {
        u32 v = (tid < 16) ? wt[tid] : 0u;
        u32 s2 = v;
#pragma unroll
        for (int off = 1; off < 16; off <<= 1) {
            u32 x = (u32)__shfl_up((int)s2, off);
            if (tid >= off) s2 += x;
        }
        if (tid < 16) wt[tid] = s2 - v;          // exclusive wave offsets
    }
    __syncthreads();
    u32 run = (sc_ - tsum) + wt[tid >> 6];
    bs[4095 - 4 * tid] = run;       run += t0;
    bs[4095 - (4 * tid + 1)] = run; run += t1;
    bs[4095 - (4 * tid + 2)] = run; run += t2;
    bs[4095 - (4 * tid + 3)] = run;
    __syncthreads();
    for (int i = tid; i < 4096; i += SORT_T) h[i] = 0u;
    __syncthreads();
    for (int i = tid; i < total; i += SORT_T) {
        u64 k = sk[i];
        u32 d = (u32)(k >> 37) & 4095u;
        u32 pos = bs[d] + atomicAdd(&h[d], 1u);
        aux[pos] = k;
    }
    __syncthreads();
    for (int p = tid; p < total; p += SORT_T) {
        u64 kp = aux[p];
        u32 d = (u32)(kp >> 37) & 4095u;
        u32 gbase = bs[d];
        u32 gend = (d == 0) ? (u32)total : bs[d - 1];
        u32 r = 0;
        for (u32 q = gbase; q < gend; ++q) r += (aux[q] > kp) ? 1u : 0u;
        sk[gbase + r] = kp;                      // unique keys -> exact slot
    }
    __syncthreads();

    for (int r = tid; r < NCAND; r += SORT_T) {
        float x1 = 0.f, y1 = 0.f, x2 = 0.f, y2 = 0.f, sc = 0.f;
        if (r < total) {
            u64 k50 = sk[r];
            int lowb = (int)(k50 & 0x3FFFFull);
            int l = 7 - (lowb >> 15);
            int idxl = 32767 - (lowb & 32767);
            int p = loff_of(l) + idxl;
            u32 key32 = (u32)(k50 >> 18);
            sc = __uint_as_float(key32 ^ 0x80000000u);
            int gp = b * N_POINTS + p;
            float l_ = reg[gp * 4 + 0] * IMG;
            float t_ = reg[gp * 4 + 1] * IMG;
            float r_ = reg[gp * 4 + 2] * IMG;
            float bb = reg[gp * 4 + 3] * IMG;
            float px = points[p * 2 + 0];
            float py = points[p * 2 + 1];
            x1 = fminf(fmaxf(px - l_, 0.0f), IMG);
            y1 = fminf(fmaxf(py - t_, 0.0f), IMG);
            x2 = fminf(fmaxf(px + r_, 0.0f), IMG);
            y2 = fminf(fmaxf(py + bb, 0.0f), IMG);
        }
        int slot = b * NCAND + r;
        sboxes[slot * 4 + 0] = x1;
        sboxes[slot * 4 + 1] = y1;
        sboxes[slot * 4 + 2] = x2;
        sboxes[slot * 4 + 3] = y2;
        sscores[slot] = sc;
    }
}

// ---------------------------------------------------------------------------
// Kernel 5: suppression-mask matrix (R8-verified row-major, 4 rows/wave).
// R10: also writes dense diag[c] (row c's diagonal-block word) — scan's
// per-word prefetch becomes one contiguous 512B load instead of a 64-line
// gather (R9 scan FETCH showed ~450 KB of scattered diagonal fills).
// ---------------------------------------------------------------------------
__global__ __launch_bounds__(256)
void mask_kernel(const float* __restrict__ sboxes,
                 const float* __restrict__ sscores,
                 u64* __restrict__ mask,
                 u64* __restrict__ diag) {
#pragma clang fp contract(off)
    const int b = blockIdx.y;
    const int wv = threadIdx.x >> 6;
    const int lane = threadIdx.x & 63;
    const int NG = (NCAND + 3) >> 2;             // 875 row-groups
    const int gidx = blockIdx.x * 4 + wv;
    if (gidx >= NG) return;
    const int c0 = gidx << 2;

    const float4* gb = (const float4*)sboxes + b * NCAND;
    const float* gs = sscores + b * NCAND;
    u64* mout = mask + (size_t)b * MASK_STRIDE;
    u64* dout = diag + (size_t)b * DIAG_STRIDE;

    float4 bc[4]; float a1[4]; bool ok[4]; int g[4]; u64* rp[4];
    bool any = false;
#pragma unroll
    for (int i = 0; i < 4; ++i) {
        int c = c0 + i;
        int cc = (c < NCAND) ? c : (NCAND - 1);
        bc[i] = gb[cc];
        a1[i] = (bc[i].z - bc[i].x) * (bc[i].w - bc[i].y);
        ok[i] = (c < NCAND) && (gs[cc] > SCORE_TH);
        g[i] = cc >> 6;
        rp[i] = mout + mask_off(cc) - g[i];
        any |= ok[i];
    }
    if (!any) return;                            // wave-uniform

    for (int w = (c0 >> 6); w < 55; ++w) {
        int cj = (w << 6) + lane;
        float4 bj = (cj < NCAND) ? gb[cj] : make_float4(0.f, 0.f, 0.f, 0.f);
        float a2 = (bj.z - bj.x) * (bj.w - bj.y);
#pragma unroll
        for (int i = 0; i < 4; ++i) {
            float x1 = fmaxf(bc[i].x, bj.x);
            float y1 = fmaxf(bc[i].y, bj.y);
            float x2 = fminf(bc[i].z, bj.z);
            float y2 = fminf(bc[i].w, bj.w);
            float inter = fmaxf(x2 - x1, 0.f) * fmaxf(y2 - y1, 0.f);
            float denom = a1[i] + a2 - inter + 1e-9f;   // ref association
            u64 bits = __ballot((double)inter > MTH * (double)denom);
            if (lane == 0 && ok[i] && w >= g[i]) {
                rp[i][w] = bits;
                if (w == g[i]) dout[c0 + i] = bits;      // dense diagonal copy
            }
        }
    }
}

// ---------------------------------------------------------------------------
// Kernel 6: sorted-order NMS scan. R10: diag prefetch (contiguous 512B/word);
// keeping lane stores its own box/score (removes 5 readlanes per keep).
// ---------------------------------------------------------------------------
__global__ __launch_bounds__(64)
void scan_kernel(const float* __restrict__ sboxes,
                 const float* __restrict__ sscores,
                 const u64* __restrict__ mask,
                 const u64* __restrict__ diag,
                 float* __restrict__ out) {
    const int b = blockIdx.x;
    const int lane = threadIdx.x;            // 64 threads = 1 wave
    const float4* gb = (const float4*)sboxes + b * NCAND;
    const float* gs = sscores + b * NCAND;
    const u64* mrow = mask + (size_t)b * MASK_STRIDE;
    const u64* drow = diag + (size_t)b * DIAG_STRIDE;

    float* ob = out + OUT_BOXES  + b * MAX_DET * 4;
    float* os = out + OUT_SCORES + b * MAX_DET;
    float* ol = out + OUT_LABELS + b * MAX_DET;
    float* ov = out + OUT_VALID  + b * MAX_DET;

    u64 m = 0ull;                            // lane f owns future-word f
    u64 rowN = drow[lane];                   // contiguous diagonal prefetch
    float4 bjN = gb[lane];
    float sjN = gs[lane];

    int kept = 0;
    for (int w = 0; w < 55; ++w) {
        const int wbase = w << 6;
        const u64 row = rowN;
        const float4 bj = bjN;
        const float sj = sjN;
        if (w < 54) {                        // prefetch next word (contiguous)
            int cn = wbase + 64 + lane;
            int cc = (cn < NCAND) ? cn : (NCAND - 1);
            rowN = drow[cc];
            bjN = gb[cc];
            float s = gs[cc];
            sjN = (cn < NCAND) ? s : 0.f;
        }
        int c = wbase + lane;
        u64 bad = __ballot(!((c < NCAND) && (sj > SCORE_TH)));
        u64 cur = readlane64(m, w) | bad;
        u64 km = 0ull;
        // phase 1: serial keeps — scalar chain (ctz + readlane64 + OR);
        // the keeping lane stores its own registers (no output readlanes)
        while (kept < MAX_DET) {
            u64 avail = ~cur;
            if (avail == 0ull) break;
            int t = (int)__builtin_ctzll(avail);       // uniform
            u64 r = readlane64(row, t);                // keep t's intra bits
            cur |= r | (1ull << t);
            km |= 1ull << t;
            if (lane == t) {
                ob[kept * 4 + 0] = bj.x;
                ob[kept * 4 + 1] = bj.y;
                ob[kept * 4 + 2] = bj.z;
                ob[kept * 4 + 3] = bj.w;
                os[kept] = sj;
                ol[kept] = 0.0f;
                ov[kept] = 1.0f;
            }
            kept++;
        }
        // phase 2: OR kept rows into future words, 8 loads per wait
        if (km) {
            const bool lr = (lane >= w && lane < 55);
            const int lo = lane - w;
            u64 acc = 0ull;
            while (km) {
#define POPBIT(tn) int tn = -1; if (km) { tn = (int)__builtin_ctzll(km); km &= km - 1ull; }
                POPBIT(t0) POPBIT(t1) POPBIT(t2) POPBIT(t3)
                POPBIT(t4) POPBIT(t5) POPBIT(t6) POPBIT(t7)
#undef POPBIT
                u64 v0 = 0, v1 = 0, v2 = 0, v3 = 0, v4 = 0, v5 = 0, v6 = 0, v7 = 0;
                if (lr) {
                    v0 = mrow[mask_off(wbase + t0) + lo];
                    if (t1 >= 0) v1 = mrow[mask_off(wbase + t1) + lo];
                    if (t2 >= 0) v2 = mrow[mask_off(wbase + t2) + lo];
                    if (t3 >= 0) v3 = mrow[mask_off(wbase + t3) + lo];
                    if (t4 >= 0) v4 = mrow[mask_off(wbase + t4) + lo];
                    if (t5 >= 0) v5 = mrow[mask_off(wbase + t5) + lo];
                    if (t6 >= 0) v6 = mrow[mask_off(wbase + t6) + lo];
                    if (t7 >= 0) v7 = mrow[mask_off(wbase + t7) + lo];
                }
                acc |= ((v0 | v1) | (v2 | v3)) | ((v4 | v5) | (v6 | v7));
            }
            m |= acc;
        }
        if (kept >= MAX_DET) break;
    }
    for (int k = kept + lane; k < MAX_DET; k += 64) {
        ob[k * 4 + 0] = 0.f; ob[k * 4 + 1] = 0.f;
        ob[k * 4 + 2] = 0.f; ob[k * 4 + 3] = 0.f;
        os[k] = 0.f; ol[k] = -1.f; ov[k] = 0.f;
    }
}

// ---------------------------------------------------------------------------
extern "C" void kernel_launch(void* const* d_in, const int* in_sizes, int n_in,
                              void* d_out, int out_size, void* d_ws, size_t ws_size,
                              hipStream_t stream) {
    const float* points = (const float*)d_in[0];
    const float* gt     = (const float*)d_in[1];
    const float* logits = (const float*)d_in[2];
    const float* reg    = (const float*)d_in[3];
    float* out = (float*)d_out;

    u32* keys   = (u32*)((char*)d_ws + WS_KEYS);
    u32* params = (u32*)((char*)d_ws + WS_PARAMS);
    u32* cnt    = (u32*)((char*)d_ws + WS_CNT);
    u64* defK   = (u64*)((char*)d_ws + WS_DEFK);
    u64* tieK   = (u64*)((char*)d_ws + WS_TIEK);
    float* sboxes  = (float*)((char*)d_ws + WS_SBOX);
    float* sscores = (float*)((char*)d_ws + WS_SSC);
    u64* mask   = (u64*)((char*)d_ws + WS_MASK);
    u64* diag   = (u64*)((char*)d_ws + WS_DIAG);

    dim3 g1((N_POINTS + 256 * MPT - 1) / (256 * MPT), BATCH);
    match_key_kernel<<<g1, 256, 0, stream>>>(points, gt, logits,
                                             out + OUT_MATCH, keys);

    hist_select_kernel<<<BATCH * NLEV, 256, 0, stream>>>(keys, params, cnt);

    compact_kernel<<<(BATCH * N_POINTS + 255) / 256, 256, 0, stream>>>(
        keys, params, cnt, defK, tieK);

    sortimg_kernel<<<BATCH, SORT_T, 0, stream>>>(params, cnt, defK, tieK,
                                                 reg, points, sboxes, sscores);

    dim3 g5(((NCAND + 3) / 4 + 3) / 4, BATCH);   // 219 x 8 blocks, 4 rows/wave
    mask_kernel<<<g5, 256, 0, stream>>>(sboxes, sscores, mask, diag);

    scan_kernel<<<BATCH, 64, 0, stream>>>(sboxes, sscores, mask, diag, out);
}

// Round 11
// 276.702 us; speedup vs baseline: 2.2582x; 1.1698x over previous
//
#include <hip/hip_runtime.h>
#include <stdint.h>

// Problem constants
#define N_POINTS   34100
#define BATCH      8
#define N_GT       200
#define NLEV       5
#define NCAND      3500
#define MAX_DET    300
#define SCORE_TH   0.05f
#define NMS_TH     0.5f
#define IMG        1280.0f
#define TIE_CAP    2048
#define NBIN       4096
// Exact threshold: RN(inter/denom) > 0.5  <=>  inter > T, T=(0.5+2^-25)*denom
// f32 fast path: r = RN(T) via fmaf(2^-25,denom,0.5*denom); only boundary
// case inter==r needs the f64 exact test (see R11 analysis). Verified absmax 0
// for the f64 form since R7.
#define MTH 0.50000002980232238769531250

// Output layout (float32 flat, reference return order)
#define OUT_MATCH  0        // 8*34100
#define OUT_BOXES  272800   // 8*300*4
#define OUT_SCORES 282400   // 8*300
#define OUT_LABELS 284800   // 8*300
#define OUT_VALID  287200   // 8*300

// Workspace layout (bytes)
#define WS_KEYS    0              // u32[8*34100]   = 1,091,200
#define WS_SBOX    2632192        // float4[8*3500] =   448,000
#define WS_SSC     3080192        // float[8*3500]  =   112,000
#define WS_MASK    3192192        // u64[8*98560]   = 6,307,840
#define WS_DIAG    9500032        // u64[8*3520]    =   225,280
#define MASK_STRIDE 98560
#define DIAG_STRIDE 3520

typedef unsigned long long u64;
typedef uint32_t u32;

// Packed upper-triangle row offset: row c stores words (c>>6)..54
__device__ __forceinline__ int mask_off(int c) {
    int g = c >> 6;
    return 64 * (55 * g - (g * (g - 1)) / 2) + (c - (g << 6)) * (55 - g);
}

__device__ __forceinline__ int loff_of(int l) {
    return (l == 0) ? 0 : (l == 1) ? 25600 : (l == 2) ? 32000 : (l == 3) ? 33600 : 34000;
}
__device__ __forceinline__ int lsize_of(int l) {
    return (l == 0) ? 25600 : (l == 1) ? 6400 : (l == 2) ? 1600 : (l == 3) ? 400 : 100;
}
__device__ __forceinline__ int k_of(int l) {
    return (l == 0) ? 1000 : (l == 1) ? 1000 : (l == 2) ? 1000 : (l == 3) ? 400 : 100;
}
__device__ __forceinline__ u64 readlane64(u64 v, int t) {
    u32 lo = (u32)__builtin_amdgcn_readlane((int)(u32)v, t);
    u32 hi = (u32)__builtin_amdgcn_readlane((int)(u32)(v >> 32), t);
    return ((u64)hi << 32) | lo;
}

// ---------------------------------------------------------------------------
// Kernel 1: point->gt matching + sigmoid sortable key (R9-verified).
// ---------------------------------------------------------------------------
#define MPT 2
__global__ __launch_bounds__(256)
void match_key_kernel(const float* __restrict__ points,
                      const float* __restrict__ gt,
                      const float* __restrict__ logits,
                      float* __restrict__ out_match,
                      u32* __restrict__ keys) {
#pragma clang fp contract(off)
    __shared__ float bx1[N_GT], by1[N_GT], bx2[N_GT], by2[N_GT], ar[N_GT];
    const int b = blockIdx.y;
    const int base = blockIdx.x * (256 * MPT) + threadIdx.x;

    for (int j = threadIdx.x; j < N_GT; j += 256) {
        float x1 = gt[(b * N_GT + j) * 4 + 0];
        float y1 = gt[(b * N_GT + j) * 4 + 1];
        float x2 = gt[(b * N_GT + j) * 4 + 2];
        float y2 = gt[(b * N_GT + j) * 4 + 3];
        bx1[j] = x1; by1[j] = y1; bx2[j] = x2; by2[j] = y2;
        ar[j] = (x2 - x1) * (y2 - y1);
    }
    __syncthreads();

    const float BIGF = 2147483648.0f;   // float32(2^31-1) rounds to 2^31
    float px[MPT], py[MPT], best[MPT];
    int bi[MPT];
#pragma unroll
    for (int k = 0; k < MPT; ++k) {
        int p = base + k * 256;
        int pc = (p < N_POINTS) ? p : 0;
        px[k] = points[pc * 2 + 0];
        py[k] = points[pc * 2 + 1];
        best[k] = BIGF; bi[k] = -1;
    }
    for (int j = 0; j < N_GT; ++j) {
        float x1 = bx1[j], y1 = by1[j], x2 = bx2[j], y2 = by2[j], a = ar[j];
#pragma unroll
        for (int k = 0; k < MPT; ++k) {
            bool inside = (px[k] >= x1) && (px[k] <= x2) &&
                          (py[k] >= y1) && (py[k] <= y2);
            float cost = inside ? a : BIGF;
            if (cost < best[k]) { best[k] = cost; bi[k] = j; }   // strict <
        }
    }
#pragma unroll
    for (int k = 0; k < MPT; ++k) {
        int p = base + k * 256;
        if (p >= N_POINTS) continue;
        out_match[b * N_POINTS + p] = (float)bi[k];
        float lg = logits[b * N_POINTS + p];
        float s = 1.0f / (1.0f + expf(-lg));
        u32 u = __float_as_uint(s);
        u32 key = (u & 0x80000000u) ? ~u : (u | 0x80000000u);
        keys[b * N_POINTS + p] = key;
    }
}

// ---------------------------------------------------------------------------
// Kernel 2: R11 MEGA pipeline — per image: for each level {LDS histogram ->
// in-block threshold select -> compact (wave-aggregated LDS counters) ->
// tie-rank}, then counting sort (R8-verified) + decode. Replaces the former
// hist_select + compact + sortimg kernels (2 fewer dispatches, no global
// atomics, no defK/tieK round-trip). LDS ~115 KB.
// ---------------------------------------------------------------------------
#define SORT_T 1024
__global__ __launch_bounds__(SORT_T)
void pipeline_kernel(const u32* __restrict__ keys,
                     const float* __restrict__ reg,
                     const float* __restrict__ points,
                     float* __restrict__ sboxes,
                     float* __restrict__ sscores) {
#pragma clang fp contract(off)
    __shared__ u64 sk[4096];
    __shared__ u64 aux[4096];
    __shared__ u64 tb[TIE_CAP];
    __shared__ u32 h[4096];
    __shared__ u32 bs[4096];
    __shared__ u32 wt[16];
    __shared__ u32 sT, skk, scnt, stcnt, stb;
    const int b = blockIdx.x;
    const int tid = threadIdx.x;
    const int lane = tid & 63;

    if (tid == 0) scnt = 0u;

    for (int l = 0; l < NLEV; ++l) {
        const int n = lsize_of(l);
        const u32 K = (u32)k_of(l);
        const u32* kl = keys + b * N_POINTS + loff_of(l);

        for (int i = tid; i < NBIN; i += SORT_T) h[i] = 0u;
        if (tid == 0) stcnt = 0u;
        __syncthreads();
        for (int i = tid; i < n; i += SORT_T)
            atomicAdd(&h[(kl[i] >> 19) & 4095u], 1u);
        __syncthreads();

        if (tid < 64) {                        // wave-0 two-level suffix scan
            u32 S = 0;
#pragma unroll 8
            for (int i = 0; i < 64; ++i) S += h[lane * 64 + i];
            u32 acc = S;
#pragma unroll
            for (int off = 1; off < 64; off <<= 1) {
                u32 v = (u32)__shfl_down((int)acc, off);
                if (lane + off < 64) acc += v;
            }
            u32 sfxAfter = acc - S;
            bool hit = (sfxAfter < K) && (sfxAfter + S >= K);
            u64 bal = __ballot(hit);
            int Lg = (int)__builtin_ctzll(bal);
            u32 sfxG = (u32)__shfl((int)sfxAfter, Lg);

            u32 v = h[Lg * 64 + lane];
            u32 acc2 = v;
#pragma unroll
            for (int off = 1; off < 64; off <<= 1) {
                u32 t = (u32)__shfl_down((int)acc2, off);
                if (lane + off < 64) acc2 += t;
            }
            u32 sfx2 = sfxG + acc2 - v;
            bool hit2 = (sfx2 < K) && (sfx2 + v >= K);
            if (hit2) { sT = (u32)(Lg * 64 + lane); skk = K - sfx2; }
        }
        __syncthreads();
        const u32 T = sT;
        const u64 below = (lane == 0) ? 0ull : (~0ull >> (64 - lane));

        // compact pass: uniform trip count so wave ballots stay aligned
        for (int i0 = tid; i0 - tid < n; i0 += SORT_T) {
            bool active = i0 < n;
            u32 key = active ? kl[i0] : 0u;
            u32 digit = (key >> 19) & 4095u;
            bool isDef = active && (digit > T);
            bool isTie = active && (digit == T);
            u64 k50 = ((u64)key << 18) | ((u64)(7 - l) << 15)
                    | (u64)(32767 - i0);
            u64 grp = __ballot(isDef);
            if (grp) {
                int leader = (int)__builtin_ctzll(grp);
                u32 base_ = 0;
                if (lane == leader)
                    base_ = atomicAdd(&scnt, (u32)__builtin_popcountll(grp));
                base_ = (u32)__shfl((int)base_, leader);
                if (isDef)
                    sk[base_ + (u32)__builtin_popcountll(grp & below)] = k50;
            }
            u64 tg = __ballot(isTie);
            if (tg) {
                int leader = (int)__builtin_ctzll(tg);
                u32 base_ = 0;
                if (lane == leader)
                    base_ = atomicAdd(&stcnt, (u32)__builtin_popcountll(tg));
                base_ = (u32)__shfl((int)base_, leader);
                if (isTie) {
                    u32 pos = base_ + (u32)__builtin_popcountll(tg & below);
                    if (pos < TIE_CAP) tb[pos] = k50;
                }
            }
        }
        __syncthreads();
        int t = (int)stcnt; if (t > TIE_CAP) t = TIE_CAP;
        const int kk = (int)skk;
        if (tid == 0) stb = atomicAdd(&scnt, (u32)kk);
        __syncthreads();
        const int tbase = (int)stb;
        for (int j = tid; j < t; j += SORT_T) {
            u64 kj = tb[j];
            int r = 0;
            for (int i = 0; i < t; ++i) r += (tb[i] > kj) ? 1 : 0;
            if (r < kk) sk[tbase + r] = kj;     // unique ranks -> exact fill
        }
        __syncthreads();
    }
    const int total = (int)scnt;                 // == 3500 by construction

    // ---- counting sort by digit (descending), exact within-digit rank ----
    for (int i = tid; i < 4096; i += SORT_T) h[i] = 0u;
    __syncthreads();
    for (int i = tid; i < total; i += SORT_T)
        atomicAdd(&h[(u32)(sk[i] >> 37) & 4095u], 1u);
    __syncthreads();

    u32 t0 = h[4095 - 4 * tid];
    u32 t1 = h[4095 - (4 * tid + 1)];
    u32 t2 = h[4095 - (4 * tid + 2)];
    u32 t3 = h[4095 - (4 * tid + 3)];
    u32 tsum = t0 + t1 + t2 + t3;
    u32 sc_ = tsum;
#pragma unroll
    for (int off = 1; off < 64; off <<= 1) {
        u32 v = (u32)__shfl_up((int)sc_, off);
        if (lane >= off) sc_ += v;
    }
    if (lane == 63) wt[tid >> 6] = sc_;
    __syncthreads();
    if (tid < 64) {
        u32 v = (tid < 16) ? wt[tid] : 0u;
        u32 s2 = v;
#pragma unroll
        for (int off = 1; off < 16; off <<= 1) {
            u32 x = (u32)__shfl_up((int)s2, off);
            if (tid >= off) s2 += x;
        }
        if (tid < 16) wt[tid] = s2 - v;          // exclusive wave offsets
    }
    __syncthreads();
    u32 run = (sc_ - tsum) + wt[tid >> 6];
    bs[4095 - 4 * tid] = run;       run += t0;
    bs[4095 - (4 * tid + 1)] = run; run += t1;
    bs[4095 - (4 * tid + 2)] = run; run += t2;
    bs[4095 - (4 * tid + 3)] = run;
    __syncthreads();
    for (int i = tid; i < 4096; i += SORT_T) h[i] = 0u;
    __syncthreads();
    for (int i = tid; i < total; i += SORT_T) {
        u64 k = sk[i];
        u32 d = (u32)(k >> 37) & 4095u;
        u32 pos = bs[d] + atomicAdd(&h[d], 1u);
        aux[pos] = k;
    }
    __syncthreads();
    for (int p = tid; p < total; p += SORT_T) {
        u64 kp = aux[p];
        u32 d = (u32)(kp >> 37) & 4095u;
        u32 gbase = bs[d];
        u32 gend = (d == 0) ? (u32)total : bs[d - 1];
        u32 r = 0;
        for (u32 q = gbase; q < gend; ++q) r += (aux[q] > kp) ? 1u : 0u;
        sk[gbase + r] = kp;                      // unique keys -> exact slot
    }
    __syncthreads();

    // decode + write sorted candidates
    for (int r = tid; r < NCAND; r += SORT_T) {
        float x1 = 0.f, y1 = 0.f, x2 = 0.f, y2 = 0.f, sc = 0.f;
        if (r < total) {
            u64 k50 = sk[r];
            int lowb = (int)(k50 & 0x3FFFFull);
            int l = 7 - (lowb >> 15);
            int idxl = 32767 - (lowb & 32767);
            int p = loff_of(l) + idxl;
            u32 key32 = (u32)(k50 >> 18);
            sc = __uint_as_float(key32 ^ 0x80000000u);
            int gp = b * N_POINTS + p;
            float l_ = reg[gp * 4 + 0] * IMG;
            float t_ = reg[gp * 4 + 1] * IMG;
            float r_ = reg[gp * 4 + 2] * IMG;
            float bb = reg[gp * 4 + 3] * IMG;
            float px = points[p * 2 + 0];
            float py = points[p * 2 + 1];
            x1 = fminf(fmaxf(px - l_, 0.0f), IMG);
            y1 = fminf(fmaxf(py - t_, 0.0f), IMG);
            x2 = fminf(fmaxf(px + r_, 0.0f), IMG);
            y2 = fminf(fmaxf(py + bb, 0.0f), IMG);
        }
        int slot = b * NCAND + r;
        sboxes[slot * 4 + 0] = x1;
        sboxes[slot * 4 + 1] = y1;
        sboxes[slot * 4 + 2] = x2;
        sboxes[slot * 4 + 3] = y2;
        sscores[slot] = sc;
    }
}

// ---------------------------------------------------------------------------
// Kernel 3: suppression-mask matrix (R8 row-major, 4 rows/wave). R11: f32
// fast-path compare (exact; boundary case inter==RN(T) falls back to f64,
// wave-uniform branch taken ~never) — removes the per-IoU f64 chain.
// ---------------------------------------------------------------------------
__global__ __launch_bounds__(256)
void mask_kernel(const float* __restrict__ sboxes,
                 const float* __restrict__ sscores,
                 u64* __restrict__ mask,
                 u64* __restrict__ diag) {
#pragma clang fp contract(off)
    const int b = blockIdx.y;
    const int wv = threadIdx.x >> 6;
    const int lane = threadIdx.x & 63;
    const int NG = (NCAND + 3) >> 2;             // 875 row-groups
    const int gidx = blockIdx.x * 4 + wv;
    if (gidx >= NG) return;
    const int c0 = gidx << 2;

    const float4* gb = (const float4*)sboxes + b * NCAND;
    const float* gs = sscores + b * NCAND;
    u64* mout = mask + (size_t)b * MASK_STRIDE;
    u64* dout = diag + (size_t)b * DIAG_STRIDE;

    float4 bc[4]; float a1[4]; bool ok[4]; int g[4]; u64* rp[4];
    bool any = false;
#pragma unroll
    for (int i = 0; i < 4; ++i) {
        int c = c0 + i;
        int cc = (c < NCAND) ? c : (NCAND - 1);
        bc[i] = gb[cc];
        a1[i] = (bc[i].z - bc[i].x) * (bc[i].w - bc[i].y);
        ok[i] = (c < NCAND) && (gs[cc] > SCORE_TH);
        g[i] = cc >> 6;
        rp[i] = mout + mask_off(cc) - g[i];
        any |= ok[i];
    }
    if (!any) return;                            // wave-uniform

    for (int w = (c0 >> 6); w < 55; ++w) {
        int cj = (w << 6) + lane;
        float4 bj = (cj < NCAND) ? gb[cj] : make_float4(0.f, 0.f, 0.f, 0.f);
        float a2 = (bj.z - bj.x) * (bj.w - bj.y);
#pragma unroll
        for (int i = 0; i < 4; ++i) {
            float x1 = fmaxf(bc[i].x, bj.x);
            float y1 = fmaxf(bc[i].y, bj.y);
            float x2 = fminf(bc[i].z, bj.z);
            float y2 = fminf(bc[i].w, bj.w);
            float inter = fmaxf(x2 - x1, 0.f) * fmaxf(y2 - y1, 0.f);
            float denom = a1[i] + a2 - inter + 1e-9f;   // ref association
            float hf = 0.5f * denom;                    // exact
            float rr = fmaf(0x1p-25f, denom, hf);       // RN(T), single rounding
            u64 bits = __ballot(inter > rr);
            u64 eq = __ballot(inter == rr);
            if (eq) {                                   // boundary: exact f64
                u64 fb = __ballot((double)inter > MTH * (double)denom);
                bits |= (eq & fb);
            }
            if (lane == 0 && ok[i] && w >= g[i]) {
                rp[i][w] = bits;
                if (w == g[i]) dout[c0 + i] = bits;     // dense diagonal copy
            }
        }
    }
}

// ---------------------------------------------------------------------------
// Kernel 4: sorted-order NMS scan (R10-verified: diag prefetch, self-store).
// ---------------------------------------------------------------------------
__global__ __launch_bounds__(64)
void scan_kernel(const float* __restrict__ sboxes,
                 const float* __restrict__ sscores,
                 const u64* __restrict__ mask,
                 const u64* __restrict__ diag,
                 float* __restrict__ out) {
    const int b = blockIdx.x;
    const int lane = threadIdx.x;            // 64 threads = 1 wave
    const float4* gb = (const float4*)sboxes + b * NCAND;
    const float* gs = sscores + b * NCAND;
    const u64* mrow = mask + (size_t)b * MASK_STRIDE;
    const u64* drow = diag + (size_t)b * DIAG_STRIDE;

    float* ob = out + OUT_BOXES  + b * MAX_DET * 4;
    float* os = out + OUT_SCORES + b * MAX_DET;
    float* ol = out + OUT_LABELS + b * MAX_DET;
    float* ov = out + OUT_VALID  + b * MAX_DET;

    u64 m = 0ull;                            // lane f owns future-word f
    u64 rowN = drow[lane];                   // contiguous diagonal prefetch
    float4 bjN = gb[lane];
    float sjN = gs[lane];

    int kept = 0;
    for (int w = 0; w < 55; ++w) {
        const int wbase = w << 6;
        const u64 row = rowN;
        const float4 bj = bjN;
        const float sj = sjN;
        if (w < 54) {                        // prefetch next word (contiguous)
            int cn = wbase + 64 + lane;
            int cc = (cn < NCAND) ? cn : (NCAND - 1);
            rowN = drow[cc];
            bjN = gb[cc];
            float s = gs[cc];
            sjN = (cn < NCAND) ? s : 0.f;
        }
        int c = wbase + lane;
        u64 bad = __ballot(!((c < NCAND) && (sj > SCORE_TH)));
        u64 cur = readlane64(m, w) | bad;
        u64 km = 0ull;
        while (kept < MAX_DET) {
            u64 avail = ~cur;
            if (avail == 0ull) break;
            int t = (int)__builtin_ctzll(avail);       // uniform
            u64 r = readlane64(row, t);                // keep t's intra bits
            cur |= r | (1ull << t);
            km |= 1ull << t;
            if (lane == t) {
                ob[kept * 4 + 0] = bj.x;
                ob[kept * 4 + 1] = bj.y;
                ob[kept * 4 + 2] = bj.z;
                ob[kept * 4 + 3] = bj.w;
                os[kept] = sj;
                ol[kept] = 0.0f;
                ov[kept] = 1.0f;
            }
            kept++;
        }
        if (km) {
            const bool lr = (lane >= w && lane < 55);
            const int lo = lane - w;
            u64 acc = 0ull;
            while (km) {
#define POPBIT(tn) int tn = -1; if (km) { tn = (int)__builtin_ctzll(km); km &= km - 1ull; }
                POPBIT(t0) POPBIT(t1) POPBIT(t2) POPBIT(t3)
                POPBIT(t4) POPBIT(t5) POPBIT(t6) POPBIT(t7)
#undef POPBIT
                u64 v0 = 0, v1 = 0, v2 = 0, v3 = 0, v4 = 0, v5 = 0, v6 = 0, v7 = 0;
                if (lr) {
                    v0 = mrow[mask_off(wbase + t0) + lo];
                    if (t1 >= 0) v1 = mrow[mask_off(wbase + t1) + lo];
                    if (t2 >= 0) v2 = mrow[mask_off(wbase + t2) + lo];
                    if (t3 >= 0) v3 = mrow[mask_off(wbase + t3) + lo];
                    if (t4 >= 0) v4 = mrow[mask_off(wbase + t4) + lo];
                    if (t5 >= 0) v5 = mrow[mask_off(wbase + t5) + lo];
                    if (t6 >= 0) v6 = mrow[mask_off(wbase + t6) + lo];
                    if (t7 >= 0) v7 = mrow[mask_off(wbase + t7) + lo];
                }
                acc |= ((v0 | v1) | (v2 | v3)) | ((v4 | v5) | (v6 | v7));
            }
            m |= acc;
        }
        if (kept >= MAX_DET) break;
    }
    for (int k = kept + lane; k < MAX_DET; k += 64) {
        ob[k * 4 + 0] = 0.f; ob[k * 4 + 1] = 0.f;
        ob[k * 4 + 2] = 0.f; ob[k * 4 + 3] = 0.f;
        os[k] = 0.f; ol[k] = -1.f; ov[k] = 0.f;
    }
}

// ---------------------------------------------------------------------------
extern "C" void kernel_launch(void* const* d_in, const int* in_sizes, int n_in,
                              void* d_out, int out_size, void* d_ws, size_t ws_size,
                              hipStream_t stream) {
    const float* points = (const float*)d_in[0];
    const float* gt     = (const float*)d_in[1];
    const float* logits = (const float*)d_in[2];
    const float* reg    = (const float*)d_in[3];
    float* out = (float*)d_out;

    u32* keys   = (u32*)((char*)d_ws + WS_KEYS);
    float* sboxes  = (float*)((char*)d_ws + WS_SBOX);
    float* sscores = (float*)((char*)d_ws + WS_SSC);
    u64* mask   = (u64*)((char*)d_ws + WS_MASK);
    u64* diag   = (u64*)((char*)d_ws + WS_DIAG);

    dim3 g1((N_POINTS + 256 * MPT - 1) / (256 * MPT), BATCH);
    match_key_kernel<<<g1, 256, 0, stream>>>(points, gt, logits,
                                             out + OUT_MATCH, keys);

    pipeline_kernel<<<BATCH, SORT_T, 0, stream>>>(keys, reg, points,
                                                  sboxes, sscores);

    dim3 g5(((NCAND + 3) / 4 + 3) / 4, BATCH);   // 219 x 8 blocks, 4 rows/wave
    mask_kernel<<<g5, 256, 0, stream>>>(sboxes, sscores, mask, diag);

    scan_kernel<<<BATCH, 64, 0, stream>>>(sboxes, sscores, mask, diag, out);
}